// Round 9
// baseline (2488.428 us; speedup 1.0000x reference)
//
#include <hip/hip_runtime.h>
#include <hip/hip_bf16.h>
#include <math.h>

#define BATCH 512
#define MAXL 128
#define HID 512
#define H3 1536

typedef __bf16 bf16x8 __attribute__((ext_vector_type(8)));
typedef __bf16 bf16x4 __attribute__((ext_vector_type(4)));
typedef float f32x4 __attribute__((ext_vector_type(4)));

// Device-coherent (MALL meeting point) ops — proven R7 path. sc0 sc1 = system scope:
// bypass stale L1/L2, always correct cross-XCD. (R8 lesson: sc0-only is NOT an
// "XCD-L2 scope" — no such architectural scope exists; it returned stale data.)
__device__ __forceinline__ bf16x8 ld_coh16(const __bf16* p) {
    bf16x8 v;
    asm volatile("global_load_dwordx4 %0, %1, off sc0 sc1"
                 : "=v"(v) : "v"((const void*)p) : "memory");
    return v;
}
__device__ __forceinline__ void st_coh16(__bf16* p, bf16x8 v) {
    asm volatile("global_store_dwordx4 %0, %1, off sc0 sc1"
                 :: "v"((void*)p), "v"(v) : "memory");
}
__device__ __forceinline__ void st_coh4(unsigned* p, unsigned v) {
    asm volatile("global_store_dword %0, %1, off sc0 sc1"
                 :: "v"((void*)p), "v"(v) : "memory");
}
__device__ __forceinline__ unsigned ld_coh4(const unsigned* p) {
    unsigned v;
    asm volatile("global_load_dword %0, %1, off sc0 sc1"
                 : "=v"(v) : "v"((const void*)p) : "memory");
    asm volatile("s_waitcnt vmcnt(0)" ::: "memory");
    return v;
}

// ---------------- prefix scan of lengths -> starts; zero barrier slots ----------------
__global__ __launch_bounds__(BATCH) void scan_kernel(const int* __restrict__ len,
                                                     int* __restrict__ starts,
                                                     unsigned* __restrict__ ctr) {
    __shared__ int buf[BATCH];
    int tid = threadIdx.x;
    ctr[tid] = 0u;                    // 16 groups x 32 slots, re-zeroed every launch
    int myLen = len[tid];
    buf[tid] = myLen;
    __syncthreads();
    for (int off = 1; off < BATCH; off <<= 1) {
        int v = (tid >= off) ? buf[tid - off] : 0;
        __syncthreads();
        buf[tid] += v;
        __syncthreads();
    }
    starts[tid] = buf[tid] - myLen;   // exclusive scan
}

// ------- h0 = segment_max(h) (fp32 + bf16 into scan buffer 0, both dirs) -------
__global__ __launch_bounds__(HID) void init_kernel(const float* __restrict__ h,
                                                   const int* __restrict__ len,
                                                   const int* __restrict__ starts,
                                                   float* __restrict__ h0,     // [B][H]
                                                   __bf16* __restrict__ hb) {  // buf0: [2][B][H]
    int b = blockIdx.x, j = threadIdx.x;
    int s = starts[b], L = len[b];
    float m = -3.4e38f;
    for (int t = 0; t < L; ++t) m = fmaxf(m, h[(size_t)(s + t) * HID + j]);
    h0[(size_t)b * HID + j] = m;
    hb[(size_t)b * HID + j] = (__bf16)m;
    hb[(size_t)(BATCH + b) * HID + j] = (__bf16)m;
}

// ---------------- message = relu(h + bias) -> bf16 ----------------
__global__ void msg_kernel(const float* __restrict__ h, const float* __restrict__ bias,
                           __bf16* __restrict__ msg, long total4) {
    for (long i = (long)blockIdx.x * blockDim.x + threadIdx.x; i < total4;
         i += (long)gridDim.x * blockDim.x) {
        float4 v = ((const float4*)h)[i];
        int c4 = (int)(i & (HID / 4 - 1));
        float4 bb = ((const float4*)bias)[c4];
        bf16x4 o;
        o[0] = (__bf16)fmaxf(v.x + bb.x, 0.f);
        o[1] = (__bf16)fmaxf(v.y + bb.y, 0.f);
        o[2] = (__bf16)fmaxf(v.z + bb.z, 0.f);
        o[3] = (__bf16)fmaxf(v.w + bb.w, 0.f);
        ((bf16x4*)msg)[i] = o;
    }
}

// ---------------- fp32 -> bf16 weight convert ----------------
__global__ void conv_kernel(const float* __restrict__ src, __bf16* __restrict__ dst, int n4) {
    int i = blockIdx.x * blockDim.x + threadIdx.x;
    if (i < n4) {
        float4 v = ((const float4*)src)[i];
        bf16x4 o;
        o[0] = (__bf16)v.x; o[1] = (__bf16)v.y; o[2] = (__bf16)v.z; o[3] = (__bf16)v.w;
        ((bf16x4*)dst)[i] = o;
    }
}

// ---------------- gx = msg @ w_ih^T  (NT GEMM, bf16 out) ----------------
__global__ __launch_bounds__(256) void gx_gemm(const __bf16* __restrict__ msg,
                                               const __bf16* __restrict__ wih,  // [2][1536][512]
                                               __bf16* __restrict__ gx,         // [2][N][1536]
                                               int N) {
    __shared__ __bf16 alds[64 * 512];
    __shared__ __bf16 tile[64][136];
    int dir = blockIdx.y;
    int r0 = blockIdx.x * 64;
    int wid = threadIdx.x >> 6, lane = threadIdx.x & 63;
    int lrow = lane & 15, lk = lane >> 4;
    const __bf16* wB = wih + (size_t)dir * H3 * HID;
    __bf16* gOut = gx + (size_t)dir * N * H3;

    for (int i = threadIdx.x; i < 64 * 64; i += 256) {
        int row = i >> 6, ch = i & 63;
        int sch = ch ^ (row & 7);
        int grow = r0 + row; if (grow >= N) grow = N - 1;
        *(bf16x8*)(&alds[row * 512 + sch * 8]) = *(const bf16x8*)(msg + (size_t)grow * HID + ch * 8);
    }
    __syncthreads();

    for (int ct = 0; ct < 12; ++ct) {
        int c0 = ct * 128 + wid * 32;
        f32x4 acc[4][2] = {};
#pragma unroll
        for (int ks = 0; ks < 16; ++ks) {
            bf16x8 b0 = *(const bf16x8*)(wB + (size_t)(c0 + lrow) * HID + ks * 32 + lk * 8);
            bf16x8 b1 = *(const bf16x8*)(wB + (size_t)(c0 + 16 + lrow) * HID + ks * 32 + lk * 8);
#pragma unroll
            for (int rf = 0; rf < 4; ++rf) {
                int row = rf * 16 + lrow;
                int sch = (ks * 4 + lk) ^ (row & 7);
                bf16x8 av = *(const bf16x8*)(&alds[row * 512 + sch * 8]);
                acc[rf][0] = __builtin_amdgcn_mfma_f32_16x16x32_bf16(av, b0, acc[rf][0], 0, 0, 0);
                acc[rf][1] = __builtin_amdgcn_mfma_f32_16x16x32_bf16(av, b1, acc[rf][1], 0, 0, 0);
            }
        }
        __syncthreads();
#pragma unroll
        for (int rf = 0; rf < 4; ++rf)
#pragma unroll
            for (int fj = 0; fj < 2; ++fj)
#pragma unroll
                for (int r = 0; r < 4; ++r)
                    tile[rf * 16 + (lane >> 4) * 4 + r][wid * 32 + fj * 16 + (lane & 15)] =
                        (__bf16)acc[rf][fj][r];
        __syncthreads();
        int row = threadIdx.x >> 2, ch = threadIdx.x & 3;
        if (r0 + row < N) {
            __bf16* d = gOut + (size_t)(r0 + row) * H3 + ct * 128 + ch * 32;
            *(bf16x8*)(d)      = *(const bf16x8*)(&tile[row][ch * 32]);
            *(bf16x8*)(d + 8)  = *(const bf16x8*)(&tile[row][ch * 32 + 8]);
            *(bf16x8*)(d + 16) = *(const bf16x8*)(&tile[row][ch * 32 + 16]);
            *(bf16x8*)(d + 24) = *(const bf16x8*)(&tile[row][ch * 32 + 24]);
        }
    }
}

// ================= persistent GRU scan, 2 interleaved chains per block =================
// 256 blocks x 256 threads. Block = (rgp(4), dir(2), hc(32)): 16 output cols, SAME dir,
// TWO row-chains: rg0=rgp, rg1=rgp+4 (shared 48KB W tile). The 16 barrier groups
// {dir,rg} are independent sequential chains; interleaving two per block hides each
// chain's barrier propagation under the other chain's compute+store (~3.5us).
// Schedule/step: W0(hidden) A0 G0 E0 S0 R0 | W1(hidden) A1 G1 E1 S1 R1 | gx prefetch.
__global__ __launch_bounds__(256, 1) void gru_scan(
    const __bf16* __restrict__ whh,   // [2][1536][512]
    const __bf16* __restrict__ gx,    // [2][N][1536]
    const float* __restrict__ h0,     // [B][H]
    __bf16* __restrict__ hb,          // [2 bufs][2 dirs][B][H]
    const float* __restrict__ b_ih_f, const float* __restrict__ b_hh_f,
    const float* __restrict__ b_ih_b, const float* __restrict__ b_hh_b,
    const int* __restrict__ len, const int* __restrict__ starts,
    unsigned* __restrict__ ctr,       // [16 groups][32 slots] u32
    float* __restrict__ out, int N) {

    __shared__ __bf16 wlds[48 * 512];   // 48KB: [gate*16+col][K], 16B-chunk XOR swizzle
    __shared__ __bf16 hout[64 * 24];    // 3KB repack tile (48B row stride)

    int bid = blockIdx.x;
    int rgp = bid & 3;
    int dir = (bid >> 2) & 1;
    int hc  = bid >> 3;                 // 0..31
    int c0  = hc * 16;
    int g0  = dir * 8 + rgp;            // chain0 barrier group
    int g1  = g0 + 4;                   // chain1 barrier group
    int r0_0 = rgp * 64;
    int r0_1 = (rgp + 4) * 64;
    int wid = threadIdx.x >> 6, lane = threadIdx.x & 63;
    int lrow = lane & 15, lk = lane >> 4;

    // ---- W tile: 48 rows (3 gates x 16 cols) x 512 K, swizzled 16B chunks ----
    for (int i = threadIdx.x; i < 48 * 64; i += 256) {
        int row = i >> 6, ch = i & 63;
        int g = row >> 4, c = row & 15;
        int sch = ch ^ (row & 7);
        const __bf16* src = whh + ((size_t)dir * H3 + (size_t)g * HID + c0 + c) * HID + ch * 8;
        *(bf16x8*)(&wlds[row * 512 + sch * 8]) = *(const bf16x8*)src;
    }

    int wr0_0 = r0_0 + wid * 16;
    int wr0_1 = r0_1 + wid * 16;
    int mycol = c0 + lrow;              // C-frag: col = lane&15
    int myrow0[4], myrow1[4];
#pragma unroll
    for (int r = 0; r < 4; ++r) {
        myrow0[r] = wr0_0 + lk * 4 + r; // C-frag: row = (lane>>4)*4 + reg
        myrow1[r] = wr0_1 + lk * 4 + r;
    }

    float hreg0[4], hreg1[4], sreg0[4], sreg1[4];
#pragma unroll
    for (int r = 0; r < 4; ++r) {
        hreg0[r] = h0[(size_t)myrow0[r] * HID + mycol];
        hreg1[r] = h0[(size_t)myrow1[r] * HID + mycol];
        sreg0[r] = 0.f; sreg1[r] = 0.f;
    }

    const float* bih = dir ? b_ih_b : b_ih_f;
    const float* bhh = dir ? b_hh_b : b_hh_f;
    float bihv[3], bhhv[3];
#pragma unroll
    for (int g = 0; g < 3; ++g) {
        bihv[g] = bih[g * HID + mycol];
        bhhv[g] = bhh[g * HID + mycol];
    }
    int mylen0[4], mystart0[4], mylen1[4], mystart1[4];
#pragma unroll
    for (int r = 0; r < 4; ++r) {
        mylen0[r] = len[myrow0[r]]; mystart0[r] = starts[myrow0[r]];
        mylen1[r] = len[myrow1[r]]; mystart1[r] = starts[myrow1[r]];
    }

    // gx prefetch for step 0 (both chains)
    float gxv0[4][3], gxv1[4][3];
    {
        int t = dir ? (MAXL - 1) : 0;
#pragma unroll
        for (int r = 0; r < 4; ++r) {
            bool re0 = t < mylen0[r], re1 = t < mylen1[r];
            size_t b0 = ((size_t)dir * N + mystart0[r] + t) * H3;
            size_t b1 = ((size_t)dir * N + mystart1[r] + t) * H3;
#pragma unroll
            for (int g = 0; g < 3; ++g) {
                gxv0[r][g] = re0 ? (float)gx[b0 + (size_t)g * HID + mycol] : 0.f;
                gxv1[r][g] = re1 ? (float)gx[b1 + (size_t)g * HID + mycol] : 0.f;
            }
        }
    }

    __syncthreads();   // wlds ready

    const size_t bufStride = (size_t)2 * BATCH * HID;

    for (int s = 0; s < MAXL; ++s) {
        int t = dir ? (MAXL - 1 - s) : s;
        const __bf16* hcur = hb + (size_t)(s & 1) * bufStride + (size_t)dir * BATCH * HID;
        __bf16* hnxt = hb + (size_t)((s + 1) & 1) * bufStride + (size_t)dir * BATCH * HID;
        bool notLast = (s + 1 < MAXL);

        // ================= chain 0 =================
        if (s) {  // W0: peers' step s-1 done (propagated during prev iter's chain1 work)
            if (threadIdx.x < 32) {
                unsigned tgt = (unsigned)s;
                while (ld_coh4(ctr + g0 * 32 + threadIdx.x) < tgt)
                    __builtin_amdgcn_s_sleep(1);
            }
            __syncthreads();
            asm volatile("" ::: "memory");
            __builtin_amdgcn_sched_barrier(0);
        }

        bf16x8 a[16];
#pragma unroll
        for (int ks = 0; ks < 16; ++ks)
            a[ks] = ld_coh16(hcur + (size_t)(wr0_0 + lrow) * HID + ks * 32 + lk * 8);
        asm volatile("s_waitcnt vmcnt(0)" ::: "memory");
        __builtin_amdgcn_sched_barrier(0);

        f32x4 acc[3] = {};
#pragma unroll
        for (int ks = 0; ks < 16; ++ks) {
#pragma unroll
            for (int g = 0; g < 3; ++g) {
                int row = g * 16 + lrow;
                int sch = (ks * 4 + lk) ^ (row & 7);
                bf16x8 b = *(const bf16x8*)(&wlds[row * 512 + sch * 8]);
                acc[g] = __builtin_amdgcn_mfma_f32_16x16x32_bf16(a[ks], b, acc[g], 0, 0, 0);
            }
        }
#pragma unroll
        for (int r = 0; r < 4; ++r) {
            float ghr = acc[0][r] + bhhv[0];
            float ghz = acc[1][r] + bhhv[1];
            float ghn = acc[2][r] + bhhv[2];
            float rg_ = 1.f / (1.f + expf(-(gxv0[r][0] + bihv[0] + ghr)));
            float zg  = 1.f / (1.f + expf(-(gxv0[r][1] + bihv[1] + ghz)));
            float ng  = tanhf(gxv0[r][2] + bihv[2] + rg_ * ghn);
            float hn  = (1.f - zg) * ng + zg * hreg0[r];
            hreg0[r] = hn;
            if (t < mylen0[r]) sreg0[r] += hn;
        }
        if (notLast) {
#pragma unroll
            for (int r = 0; r < 4; ++r)
                hout[(wid * 16 + lk * 4 + r) * 24 + lrow] = (__bf16)hreg0[r];
            __syncthreads();
            if (threadIdx.x < 128) {
                int row = threadIdx.x >> 1, half = threadIdx.x & 1;
                st_coh16(hnxt + (size_t)(r0_0 + row) * HID + c0 + half * 8,
                         *(const bf16x8*)(&hout[row * 24 + half * 8]));
            }
            asm volatile("s_waitcnt vmcnt(0)" ::: "memory");
            __syncthreads();
            if (threadIdx.x == 0) st_coh4(ctr + g0 * 32 + hc, (unsigned)(s + 1));
        }

        // ================= chain 1 =================
        if (s) {  // W1: propagated during chain0's work just now
            if (threadIdx.x < 32) {
                unsigned tgt = (unsigned)s;
                while (ld_coh4(ctr + g1 * 32 + threadIdx.x) < tgt)
                    __builtin_amdgcn_s_sleep(1);
            }
            __syncthreads();
            asm volatile("" ::: "memory");
            __builtin_amdgcn_sched_barrier(0);
        } else {
            __syncthreads();   // protect hout reuse at s==0 (no W1 sync present)
        }

#pragma unroll
        for (int ks = 0; ks < 16; ++ks)
            a[ks] = ld_coh16(hcur + (size_t)(wr0_1 + lrow) * HID + ks * 32 + lk * 8);
        asm volatile("s_waitcnt vmcnt(0)" ::: "memory");
        __builtin_amdgcn_sched_barrier(0);

        f32x4 acc1[3] = {};
#pragma unroll
        for (int ks = 0; ks < 16; ++ks) {
#pragma unroll
            for (int g = 0; g < 3; ++g) {
                int row = g * 16 + lrow;
                int sch = (ks * 4 + lk) ^ (row & 7);
                bf16x8 b = *(const bf16x8*)(&wlds[row * 512 + sch * 8]);
                acc1[g] = __builtin_amdgcn_mfma_f32_16x16x32_bf16(a[ks], b, acc1[g], 0, 0, 0);
            }
        }
#pragma unroll
        for (int r = 0; r < 4; ++r) {
            float ghr = acc1[0][r] + bhhv[0];
            float ghz = acc1[1][r] + bhhv[1];
            float ghn = acc1[2][r] + bhhv[2];
            float rg_ = 1.f / (1.f + expf(-(gxv1[r][0] + bihv[0] + ghr)));
            float zg  = 1.f / (1.f + expf(-(gxv1[r][1] + bihv[1] + ghz)));
            float ng  = tanhf(gxv1[r][2] + bihv[2] + rg_ * ghn);
            float hn  = (1.f - zg) * ng + zg * hreg1[r];
            hreg1[r] = hn;
            if (t < mylen1[r]) sreg1[r] += hn;
        }
        if (notLast) {
#pragma unroll
            for (int r = 0; r < 4; ++r)
                hout[(wid * 16 + lk * 4 + r) * 24 + lrow] = (__bf16)hreg1[r];
            __syncthreads();
            if (threadIdx.x < 128) {
                int row = threadIdx.x >> 1, half = threadIdx.x & 1;
                st_coh16(hnxt + (size_t)(r0_1 + row) * HID + c0 + half * 8,
                         *(const bf16x8*)(&hout[row * 24 + half * 8]));
            }
            asm volatile("s_waitcnt vmcnt(0)" ::: "memory");
            __syncthreads();
            if (threadIdx.x == 0) st_coh4(ctr + g1 * 32 + hc, (unsigned)(s + 1));

            // gx prefetch for step s+1 (both chains) — overlaps next iter's W0
            int tn = dir ? (MAXL - 2 - s) : (s + 1);
#pragma unroll
            for (int r = 0; r < 4; ++r) {
                bool re0 = tn < mylen0[r], re1 = tn < mylen1[r];
                size_t b0 = ((size_t)dir * N + mystart0[r] + tn) * H3;
                size_t b1 = ((size_t)dir * N + mystart1[r] + tn) * H3;
#pragma unroll
                for (int g = 0; g < 3; ++g) {
                    gxv0[r][g] = re0 ? (float)gx[b0 + (size_t)g * HID + mycol] : 0.f;
                    gxv1[r][g] = re1 ? (float)gx[b1 + (size_t)g * HID + mycol] : 0.f;
                }
            }
        }
    }

    // ---- final output: out[row][dir*H + col] = sum / len
#pragma unroll
    for (int r = 0; r < 4; ++r) {
        out[(size_t)myrow0[r] * (2 * HID) + (size_t)dir * HID + mycol] =
            sreg0[r] / (float)mylen0[r];
        out[(size_t)myrow1[r] * (2 * HID) + (size_t)dir * HID + mycol] =
            sreg1[r] / (float)mylen1[r];
    }
}

extern "C" void kernel_launch(void* const* d_in, const int* in_sizes, int n_in,
                              void* d_out, int out_size, void* d_ws, size_t ws_size,
                              hipStream_t stream) {
    const float* h      = (const float*)d_in[0];
    const int*   lens   = (const int*)d_in[1];
    const float* bias   = (const float*)d_in[2];
    const float* w_ih_f = (const float*)d_in[3];
    const float* w_hh_f = (const float*)d_in[4];
    const float* b_ih_f = (const float*)d_in[5];
    const float* b_hh_f = (const float*)d_in[6];
    const float* w_ih_b = (const float*)d_in[7];
    const float* w_hh_b = (const float*)d_in[8];
    const float* b_ih_b = (const float*)d_in[9];
    const float* b_hh_b = (const float*)d_in[10];
    float* out = (float*)d_out;
    const int N = in_sizes[0] / HID;

    char* p = (char*)d_ws;
    size_t off = 0;
    int* starts   = (int*)(p + off);        off += 4096;
    unsigned* ctr = (unsigned*)(p + off);   off += 4096;   // 16 groups x 32 slots
    float* h0   = (float*)(p + off);        off += (size_t)BATCH * HID * 4;
    __bf16* hb  = (__bf16*)(p + off);       off += (size_t)2 * 2 * BATCH * HID * 2;
    __bf16* wih = (__bf16*)(p + off);       off += (size_t)2 * H3 * HID * 2;
    __bf16* whh = (__bf16*)(p + off);       off += (size_t)2 * H3 * HID * 2;
    __bf16* msg = (__bf16*)(p + off);       off += (size_t)N * HID * 2;
    __bf16* gx  = (__bf16*)(p + off);       off += (size_t)2 * N * H3 * 2;
    if (off > ws_size) return;

    scan_kernel<<<1, BATCH, 0, stream>>>(lens, starts, ctr);
    init_kernel<<<BATCH, HID, 0, stream>>>(h, lens, starts, h0, hb);

    long total4 = (long)N * HID / 4;
    int msgBlocks = (int)((total4 + 255) / 256); if (msgBlocks > 2048) msgBlocks = 2048;
    msg_kernel<<<msgBlocks, 256, 0, stream>>>(h, bias, msg, total4);

    int n4 = H3 * HID / 4;
    int cb = (n4 + 255) / 256;
    conv_kernel<<<cb, 256, 0, stream>>>(w_ih_f, wih, n4);
    conv_kernel<<<cb, 256, 0, stream>>>(w_ih_b, wih + (size_t)H3 * HID, n4);
    conv_kernel<<<cb, 256, 0, stream>>>(w_hh_f, whh, n4);
    conv_kernel<<<cb, 256, 0, stream>>>(w_hh_b, whh + (size_t)H3 * HID, n4);

    gx_gemm<<<dim3((N + 63) / 64, 2), 256, 0, stream>>>(msg, wih, gx, N);

    int Nv = N;
    void* kargs[] = {(void*)&whh, (void*)&gx, (void*)&h0, (void*)&hb,
                     (void*)&b_ih_f, (void*)&b_hh_f, (void*)&b_ih_b, (void*)&b_hh_b,
                     (void*)&lens, (void*)&starts, (void*)&ctr, (void*)&out, (void*)&Nv};
    hipLaunchCooperativeKernel((const void*)gru_scan, dim3(256), dim3(256), kargs, 0, stream);
}

// Round 12
// 1877.040 us; speedup vs baseline: 1.3257x; 1.3257x over previous
//
#include <hip/hip_runtime.h>
#include <hip/hip_bf16.h>
#include <math.h>

#define BATCH 512
#define MAXL 128
#define HID 512
#define H3 1536

typedef __bf16 bf16x8 __attribute__((ext_vector_type(8)));
typedef __bf16 bf16x4 __attribute__((ext_vector_type(4)));
typedef float f32x4 __attribute__((ext_vector_type(4)));

// Device-coherent (MALL meeting point) ops — proven R6/R7 path. sc0 sc1 bypasses
// stale L1/L2; always correct cross-XCD.
__device__ __forceinline__ bf16x8 ld_coh16(const __bf16* p) {
    bf16x8 v;
    asm volatile("global_load_dwordx4 %0, %1, off sc0 sc1"
                 : "=v"(v) : "v"((const void*)p) : "memory");
    return v;
}
__device__ __forceinline__ void st_coh16(__bf16* p, bf16x8 v) {
    asm volatile("global_store_dwordx4 %0, %1, off sc0 sc1"
                 :: "v"((void*)p), "v"(v) : "memory");
}
__device__ __forceinline__ void st_coh4(unsigned* p, unsigned v) {
    asm volatile("global_store_dword %0, %1, off sc0 sc1"
                 :: "v"((void*)p), "v"(v) : "memory");
}
__device__ __forceinline__ unsigned ld_coh4(const unsigned* p) {
    unsigned v;
    asm volatile("global_load_dword %0, %1, off sc0 sc1"
                 : "=v"(v) : "v"((const void*)p) : "memory");
    asm volatile("s_waitcnt vmcnt(0)" ::: "memory");
    return v;
}

// ---------------- prefix scan of lengths -> starts; zero barrier slots ----------------
__global__ __launch_bounds__(BATCH) void scan_kernel(const int* __restrict__ len,
                                                     int* __restrict__ starts,
                                                     unsigned* __restrict__ ctr) {
    __shared__ int buf[BATCH];
    int tid = threadIdx.x;
    ctr[tid] = 0u;                    // 1024 slots: [16 grp][4 wid][16 hc]
    ctr[tid + BATCH] = 0u;            // re-zeroed every launch (graph-replay determinism)
    int myLen = len[tid];
    buf[tid] = myLen;
    __syncthreads();
    for (int off = 1; off < BATCH; off <<= 1) {
        int v = (tid >= off) ? buf[tid - off] : 0;
        __syncthreads();
        buf[tid] += v;
        __syncthreads();
    }
    starts[tid] = buf[tid] - myLen;   // exclusive scan
}

// ------- h0 = segment_max(h) (fp32 + bf16 into scan buffer 0, both dirs) -------
__global__ __launch_bounds__(HID) void init_kernel(const float* __restrict__ h,
                                                   const int* __restrict__ len,
                                                   const int* __restrict__ starts,
                                                   float* __restrict__ h0,     // [B][H]
                                                   __bf16* __restrict__ hb) {  // buf0: [2][B][H]
    int b = blockIdx.x, j = threadIdx.x;
    int s = starts[b], L = len[b];
    float m = -3.4e38f;
    for (int t = 0; t < L; ++t) m = fmaxf(m, h[(size_t)(s + t) * HID + j]);
    h0[(size_t)b * HID + j] = m;
    hb[(size_t)b * HID + j] = (__bf16)m;
    hb[(size_t)(BATCH + b) * HID + j] = (__bf16)m;
}

// ---------------- message = relu(h + bias) -> bf16 ----------------
__global__ void msg_kernel(const float* __restrict__ h, const float* __restrict__ bias,
                           __bf16* __restrict__ msg, long total4) {
    for (long i = (long)blockIdx.x * blockDim.x + threadIdx.x; i < total4;
         i += (long)gridDim.x * blockDim.x) {
        float4 v = ((const float4*)h)[i];
        int c4 = (int)(i & (HID / 4 - 1));
        float4 bb = ((const float4*)bias)[c4];
        bf16x4 o;
        o[0] = (__bf16)fmaxf(v.x + bb.x, 0.f);
        o[1] = (__bf16)fmaxf(v.y + bb.y, 0.f);
        o[2] = (__bf16)fmaxf(v.z + bb.z, 0.f);
        o[3] = (__bf16)fmaxf(v.w + bb.w, 0.f);
        ((bf16x4*)msg)[i] = o;
    }
}

// ---------------- fp32 -> bf16 weight convert ----------------
__global__ void conv_kernel(const float* __restrict__ src, __bf16* __restrict__ dst, int n4) {
    int i = blockIdx.x * blockDim.x + threadIdx.x;
    if (i < n4) {
        float4 v = ((const float4*)src)[i];
        bf16x4 o;
        o[0] = (__bf16)v.x; o[1] = (__bf16)v.y; o[2] = (__bf16)v.z; o[3] = (__bf16)v.w;
        ((bf16x4*)dst)[i] = o;
    }
}

// ---------------- gx = msg @ w_ih^T  (NT GEMM, bf16 out) ----------------
__global__ __launch_bounds__(256) void gx_gemm(const __bf16* __restrict__ msg,
                                               const __bf16* __restrict__ wih,  // [2][1536][512]
                                               __bf16* __restrict__ gx,         // [2][N][1536]
                                               int N) {
    __shared__ __bf16 alds[64 * 512];
    __shared__ __bf16 tile[64][136];
    int dir = blockIdx.y;
    int r0 = blockIdx.x * 64;
    int wid = threadIdx.x >> 6, lane = threadIdx.x & 63;
    int lrow = lane & 15, lk = lane >> 4;
    const __bf16* wB = wih + (size_t)dir * H3 * HID;
    __bf16* gOut = gx + (size_t)dir * N * H3;

    for (int i = threadIdx.x; i < 64 * 64; i += 256) {
        int row = i >> 6, ch = i & 63;
        int sch = ch ^ (row & 7);
        int grow = r0 + row; if (grow >= N) grow = N - 1;
        *(bf16x8*)(&alds[row * 512 + sch * 8]) = *(const bf16x8*)(msg + (size_t)grow * HID + ch * 8);
    }
    __syncthreads();

    for (int ct = 0; ct < 12; ++ct) {
        int c0 = ct * 128 + wid * 32;
        f32x4 acc[4][2] = {};
#pragma unroll
        for (int ks = 0; ks < 16; ++ks) {
            bf16x8 b0 = *(const bf16x8*)(wB + (size_t)(c0 + lrow) * HID + ks * 32 + lk * 8);
            bf16x8 b1 = *(const bf16x8*)(wB + (size_t)(c0 + 16 + lrow) * HID + ks * 32 + lk * 8);
#pragma unroll
            for (int rf = 0; rf < 4; ++rf) {
                int row = rf * 16 + lrow;
                int sch = (ks * 4 + lk) ^ (row & 7);
                bf16x8 av = *(const bf16x8*)(&alds[row * 512 + sch * 8]);
                acc[rf][0] = __builtin_amdgcn_mfma_f32_16x16x32_bf16(av, b0, acc[rf][0], 0, 0, 0);
                acc[rf][1] = __builtin_amdgcn_mfma_f32_16x16x32_bf16(av, b1, acc[rf][1], 0, 0, 0);
            }
        }
        __syncthreads();
#pragma unroll
        for (int rf = 0; rf < 4; ++rf)
#pragma unroll
            for (int fj = 0; fj < 2; ++fj)
#pragma unroll
                for (int r = 0; r < 4; ++r)
                    tile[rf * 16 + (lane >> 4) * 4 + r][wid * 32 + fj * 16 + (lane & 15)] =
                        (__bf16)acc[rf][fj][r];
        __syncthreads();
        int row = threadIdx.x >> 2, ch = threadIdx.x & 3;
        if (r0 + row < N) {
            __bf16* d = gOut + (size_t)(r0 + row) * H3 + ct * 128 + ch * 32;
            *(bf16x8*)(d)      = *(const bf16x8*)(&tile[row][ch * 32]);
            *(bf16x8*)(d + 8)  = *(const bf16x8*)(&tile[row][ch * 32 + 8]);
            *(bf16x8*)(d + 16) = *(const bf16x8*)(&tile[row][ch * 32 + 16]);
            *(bf16x8*)(d + 24) = *(const bf16x8*)(&tile[row][ch * 32 + 24]);
        }
    }
}

// ================= persistent GRU scan — PER-WAVE flags & exchange =================
// 256 blocks x 256 threads (coop for co-residency). Block = (dir, rg(8), hc(16)).
// Rows are partitioned by wid, so the dependency graph decomposes into 64
// independent chains of 16 waves (2dir x 8rg x 4wid). Each wave: repacks its own
// 16x32 tile (private LDS, wave-internal ordering), stores it, drains ITS OWN
// vmcnt (per-wave counter), lane0 writes flag slot [grp][wid][hc]; poll watches
// only the 16 same-wid slots (one 64B line). NO __syncthreads in the loop —
// intra-block skew no longer gates anything.
__global__ __launch_bounds__(256, 1) void gru_scan(
    const __bf16* __restrict__ whh,   // [2][1536][512]
    const __bf16* __restrict__ gx,    // [2][N][1536]
    const float* __restrict__ h0,     // [B][H]
    __bf16* __restrict__ hb,          // [2 bufs][2 dirs][B][H]
    const float* __restrict__ b_ih_f, const float* __restrict__ b_hh_f,
    const float* __restrict__ b_ih_b, const float* __restrict__ b_hh_b,
    const int* __restrict__ len, const int* __restrict__ starts,
    unsigned* __restrict__ ctr,       // [16 grp][4 wid][16 hc] u32 = 4KB
    float* __restrict__ out, int N) {

    __shared__ __bf16 wlds[96 * 512];    // 96KB W tile, 16B-chunk XOR swizzle
    __shared__ __bf16 hout[4][16 * 40];  // per-wave private repack (no cross-wave sync)

    int bid = blockIdx.x;
    int rg  = bid & 7;
    int dir = (bid >> 3) & 1;
    int hc  = bid >> 4;
    int grp = dir * 8 + rg;
    int wid = threadIdx.x >> 6, lane = threadIdx.x & 63;
    int r0 = rg * 64;
    int c0 = hc * 32;

    for (int i = threadIdx.x; i < 96 * 64; i += 256) {
        int row = i >> 6, ch = i & 63;
        int g = row >> 5, c = row & 31;
        int sch = ch ^ (row & 7);
        const __bf16* src = whh + ((size_t)dir * H3 + (size_t)g * HID + c0 + c) * HID + ch * 8;
        *(bf16x8*)(&wlds[row * 512 + sch * 8]) = *(const bf16x8*)src;
    }

    int wr0 = r0 + wid * 16;
    int lrow = lane & 15;
    int lk   = lane >> 4;

    int mycol[2], myrow[4];
#pragma unroll
    for (int fj = 0; fj < 2; ++fj) mycol[fj] = c0 + fj * 16 + (lane & 15);
#pragma unroll
    for (int r = 0; r < 4; ++r) myrow[r] = wr0 + (lane >> 4) * 4 + r;

    float hreg[2][4], sreg[2][4];
#pragma unroll
    for (int fj = 0; fj < 2; ++fj)
#pragma unroll
        for (int r = 0; r < 4; ++r) {
            hreg[fj][r] = h0[(size_t)myrow[r] * HID + mycol[fj]];
            sreg[fj][r] = 0.f;
        }

    const float* bih = dir ? b_ih_b : b_ih_f;
    const float* bhh = dir ? b_hh_b : b_hh_f;
    float bihv[2][3], bhhv[2][3];
#pragma unroll
    for (int fj = 0; fj < 2; ++fj)
#pragma unroll
        for (int g = 0; g < 3; ++g) {
            bihv[fj][g] = bih[g * HID + mycol[fj]];
            bhhv[fj][g] = bhh[g * HID + mycol[fj]];
        }
    int mylen[4], mystart[4];
#pragma unroll
    for (int r = 0; r < 4; ++r) { mylen[r] = len[myrow[r]]; mystart[r] = starts[myrow[r]]; }

    // gx prefetch for step 0
    float gxv[2][4][3];
    {
        int t = dir ? (MAXL - 1) : 0;
#pragma unroll
        for (int r = 0; r < 4; ++r) {
            bool real = t < mylen[r];
            size_t base = ((size_t)dir * N + mystart[r] + t) * H3;
#pragma unroll
            for (int fj = 0; fj < 2; ++fj)
#pragma unroll
                for (int g = 0; g < 3; ++g)
                    gxv[fj][r][g] = real ? (float)gx[base + (size_t)g * HID + mycol[fj]] : 0.f;
        }
    }

    __syncthreads();   // wlds ready — only block-wide sync in this kernel

    const size_t bufStride = (size_t)2 * BATCH * HID;
    // per-lane store coords: row = wr0 + (lane>>2), 8-col chunk = lane&3
    const size_t stoff = (size_t)(wr0 + (lane >> 2)) * HID + c0 + (lane & 3) * 8;
    unsigned* myArrive = ctr + grp * 64 + wid * 16 + hc;
    const unsigned* myPoll = ctr + grp * 64 + wid * 16 + (lane & 15);

    for (int s = 0; s < MAXL; ++s) {
        int t = dir ? (MAXL - 1 - s) : s;
        const __bf16* hcur = hb + (size_t)(s & 1) * bufStride + (size_t)dir * BATCH * HID;
        __bf16* hnxt = hb + (size_t)((s + 1) & 1) * bufStride + (size_t)dir * BATCH * HID;

        // ---- A: this wave's [16 rows x 512 K] via coherent 16B loads, all in flight
        bf16x8 a[16];
#pragma unroll
        for (int ks = 0; ks < 16; ++ks)
            a[ks] = ld_coh16(hcur + (size_t)(wr0 + lrow) * HID + ks * 32 + lk * 8);
        asm volatile("s_waitcnt vmcnt(0)" ::: "memory");
        __builtin_amdgcn_sched_barrier(0);   // keep MFMAs below the waitcnt (rule 18)

        // ---- GEMM: gh = h @ whh^T, 3 gates x 2 col-frags
        f32x4 acc[3][2] = {};
#pragma unroll
        for (int ks = 0; ks < 16; ++ks) {
#pragma unroll
            for (int g = 0; g < 3; ++g) {
#pragma unroll
                for (int f = 0; f < 2; ++f) {
                    int row = g * 32 + f * 16 + lrow;
                    int sch = (ks * 4 + lk) ^ (row & 7);
                    bf16x8 b = *(const bf16x8*)(&wlds[row * 512 + sch * 8]);
                    acc[g][f] = __builtin_amdgcn_mfma_f32_16x16x32_bf16(a[ks], b, acc[g][f], 0, 0, 0);
                }
            }
        }

        // ---- gate math + state update (fp32, registers)
#pragma unroll
        for (int fj = 0; fj < 2; ++fj)
#pragma unroll
            for (int r = 0; r < 4; ++r) {
                float ghr = acc[0][fj][r] + bhhv[fj][0];
                float ghz = acc[1][fj][r] + bhhv[fj][1];
                float ghn = acc[2][fj][r] + bhhv[fj][2];
                float xr = gxv[fj][r][0] + bihv[fj][0];
                float xz = gxv[fj][r][1] + bihv[fj][1];
                float xn = gxv[fj][r][2] + bihv[fj][2];
                float rg_ = 1.f / (1.f + expf(-(xr + ghr)));
                float zg  = 1.f / (1.f + expf(-(xz + ghz)));
                float ng  = tanhf(xn + rg_ * ghn);
                float hn  = (1.f - zg) * ng + zg * hreg[fj][r];
                hreg[fj][r] = hn;
                if (t < mylen[r]) sreg[fj][r] += hn;
            }

        if (s + 1 == MAXL) break;   // no exchange after last step

        // ---- per-wave repack (wave-internal LDS ordering) + per-wave 16B stores
#pragma unroll
        for (int fj = 0; fj < 2; ++fj)
#pragma unroll
            for (int r = 0; r < 4; ++r)
                hout[wid][(lk * 4 + r) * 40 + fj * 16 + lrow] = (__bf16)hreg[fj][r];
        {
            bf16x8 v = *(const bf16x8*)(&hout[wid][(lane >> 2) * 40 + (lane & 3) * 8]);
            st_coh16(hnxt + stoff, v);
        }
        // drain THIS WAVE's store (per-wave vmcnt), then arrive on own slot
        asm volatile("s_waitcnt vmcnt(0)" ::: "memory");
        if (lane == 0) st_coh4(myArrive, (unsigned)(s + 1));

        // gx prefetch for step s+1 — flies under the poll
        {
            int tn = dir ? (MAXL - 2 - s) : (s + 1);
#pragma unroll
            for (int r = 0; r < 4; ++r) {
                bool real = tn < mylen[r];
                size_t base = ((size_t)dir * N + mystart[r] + tn) * H3;
#pragma unroll
                for (int fj = 0; fj < 2; ++fj)
#pragma unroll
                    for (int g = 0; g < 3; ++g)
                        gxv[fj][r][g] = real ? (float)gx[base + (size_t)g * HID + mycol[fj]] : 0.f;
            }
        }

        // ---- poll: all lanes watch the 16 same-wid slots (one 64B line)
        {
            unsigned tgt = (unsigned)(s + 1);
            for (;;) {
                unsigned v = ld_coh4(myPoll);
                if (__ballot(v < tgt) == 0ull) break;
                __builtin_amdgcn_s_sleep(1);
            }
        }
        asm volatile("" ::: "memory");       // no compiler motion across the spin exit
        __builtin_amdgcn_sched_barrier(0);   // keep next A-loads after it
    }

    // ---- final output: out[row][dir*H + col] = sum / len
#pragma unroll
    for (int fj = 0; fj < 2; ++fj)
#pragma unroll
        for (int r = 0; r < 4; ++r)
            out[(size_t)myrow[r] * (2 * HID) + (size_t)dir * HID + mycol[fj]] =
                sreg[fj][r] / (float)mylen[r];
}

extern "C" void kernel_launch(void* const* d_in, const int* in_sizes, int n_in,
                              void* d_out, int out_size, void* d_ws, size_t ws_size,
                              hipStream_t stream) {
    const float* h      = (const float*)d_in[0];
    const int*   lens   = (const int*)d_in[1];
    const float* bias   = (const float*)d_in[2];
    const float* w_ih_f = (const float*)d_in[3];
    const float* w_hh_f = (const float*)d_in[4];
    const float* b_ih_f = (const float*)d_in[5];
    const float* b_hh_f = (const float*)d_in[6];
    const float* w_ih_b = (const float*)d_in[7];
    const float* w_hh_b = (const float*)d_in[8];
    const float* b_ih_b = (const float*)d_in[9];
    const float* b_hh_b = (const float*)d_in[10];
    float* out = (float*)d_out;
    const int N = in_sizes[0] / HID;

    // workspace layout — identical to the R6/R7 passing layout (~245MB, known to fit)
    char* p = (char*)d_ws;
    size_t off = 0;
    int* starts   = (int*)(p + off);        off += 4096;
    unsigned* ctr = (unsigned*)(p + off);   off += 4096;   // 1024 u32 flag slots
    float* h0   = (float*)(p + off);        off += (size_t)BATCH * HID * 4;
    __bf16* hb  = (__bf16*)(p + off);       off += (size_t)2 * 2 * BATCH * HID * 2;
    __bf16* wih = (__bf16*)(p + off);       off += (size_t)2 * H3 * HID * 2;
    __bf16* whh = (__bf16*)(p + off);       off += (size_t)2 * H3 * HID * 2;
    __bf16* msg = (__bf16*)(p + off);       off += (size_t)N * HID * 2;
    __bf16* gx  = (__bf16*)(p + off);       off += (size_t)2 * N * H3 * 2;
    if (off > ws_size) return;  // interpretable failure: output stays zero

    scan_kernel<<<1, BATCH, 0, stream>>>(lens, starts, ctr);
    init_kernel<<<BATCH, HID, 0, stream>>>(h, lens, starts, h0, hb);

    long total4 = (long)N * HID / 4;
    int msgBlocks = (int)((total4 + 255) / 256); if (msgBlocks > 2048) msgBlocks = 2048;
    msg_kernel<<<msgBlocks, 256, 0, stream>>>(h, bias, msg, total4);

    int n4 = H3 * HID / 4;
    int cb = (n4 + 255) / 256;
    conv_kernel<<<cb, 256, 0, stream>>>(w_ih_f, wih, n4);
    conv_kernel<<<cb, 256, 0, stream>>>(w_ih_b, wih + (size_t)H3 * HID, n4);
    conv_kernel<<<cb, 256, 0, stream>>>(w_hh_f, whh, n4);
    conv_kernel<<<cb, 256, 0, stream>>>(w_hh_b, whh + (size_t)H3 * HID, n4);

    gx_gemm<<<dim3((N + 63) / 64, 2), 256, 0, stream>>>(msg, wih, gx, N);

    int Nv = N;
    void* kargs[] = {(void*)&whh, (void*)&gx, (void*)&h0, (void*)&hb,
                     (void*)&b_ih_f, (void*)&b_hh_f, (void*)&b_ih_b, (void*)&b_hh_b,
                     (void*)&lens, (void*)&starts, (void*)&ctr, (void*)&out, (void*)&Nv};
    hipLaunchCooperativeKernel((const void*)gru_scan, dim3(256), dim3(256), kargs, 0, stream);
}

// Round 14
// 1855.730 us; speedup vs baseline: 1.3409x; 1.0115x over previous
//
#include <hip/hip_runtime.h>
#include <hip/hip_bf16.h>
#include <math.h>

#define BATCH 512
#define MAXL 128
#define HID 512
#define H3 1536

typedef __bf16 bf16x8 __attribute__((ext_vector_type(8)));
typedef __bf16 bf16x4 __attribute__((ext_vector_type(4)));
typedef float f32x4 __attribute__((ext_vector_type(4)));

// Device-coherent (MALL meeting point) ops — proven R6/R7/R12 path. sc0 sc1 bypasses
// stale L1/L2; always correct cross-XCD.
__device__ __forceinline__ bf16x8 ld_coh16(const __bf16* p) {
    bf16x8 v;
    asm volatile("global_load_dwordx4 %0, %1, off sc0 sc1"
                 : "=v"(v) : "v"((const void*)p) : "memory");
    return v;
}
__device__ __forceinline__ void st_coh16(__bf16* p, bf16x8 v) {
    asm volatile("global_store_dwordx4 %0, %1, off sc0 sc1"
                 :: "v"((void*)p), "v"(v) : "memory");
}
__device__ __forceinline__ void st_coh4(unsigned* p, unsigned v) {
    asm volatile("global_store_dword %0, %1, off sc0 sc1"
                 :: "v"((void*)p), "v"(v) : "memory");
}
__device__ __forceinline__ unsigned ld_coh4(const unsigned* p) {
    unsigned v;
    asm volatile("global_load_dword %0, %1, off sc0 sc1"
                 : "=v"(v) : "v"((const void*)p) : "memory");
    asm volatile("s_waitcnt vmcnt(0)" ::: "memory");
    return v;
}

// ---------------- prefix scan of lengths -> starts; zero barrier slots ----------------
__global__ __launch_bounds__(BATCH) void scan_kernel(const int* __restrict__ len,
                                                     int* __restrict__ starts,
                                                     unsigned* __restrict__ ctr) {
    __shared__ int buf[BATCH];
    int tid = threadIdx.x;
    ctr[tid] = 0u;                    // 1024 slots: [16 grp][4 wid][16 hc]
    ctr[tid + BATCH] = 0u;            // re-zeroed every launch (graph-replay determinism)
    int myLen = len[tid];
    buf[tid] = myLen;
    __syncthreads();
    for (int off = 1; off < BATCH; off <<= 1) {
        int v = (tid >= off) ? buf[tid - off] : 0;
        __syncthreads();
        buf[tid] += v;
        __syncthreads();
    }
    starts[tid] = buf[tid] - myLen;   // exclusive scan
}

// ------- h0 = segment_max(h) (fp32 + bf16 into scan buffer 0, both dirs) -------
__global__ __launch_bounds__(HID) void init_kernel(const float* __restrict__ h,
                                                   const int* __restrict__ len,
                                                   const int* __restrict__ starts,
                                                   float* __restrict__ h0,     // [B][H]
                                                   __bf16* __restrict__ hb) {  // buf0: [2][B][H]
    int b = blockIdx.x, j = threadIdx.x;
    int s = starts[b], L = len[b];
    float m = -3.4e38f;
    for (int t = 0; t < L; ++t) m = fmaxf(m, h[(size_t)(s + t) * HID + j]);
    h0[(size_t)b * HID + j] = m;
    hb[(size_t)b * HID + j] = (__bf16)m;
    hb[(size_t)(BATCH + b) * HID + j] = (__bf16)m;
}

// ---------------- message = relu(h + bias) -> bf16 ----------------
__global__ void msg_kernel(const float* __restrict__ h, const float* __restrict__ bias,
                           __bf16* __restrict__ msg, long total4) {
    for (long i = (long)blockIdx.x * blockDim.x + threadIdx.x; i < total4;
         i += (long)gridDim.x * blockDim.x) {
        float4 v = ((const float4*)h)[i];
        int c4 = (int)(i & (HID / 4 - 1));
        float4 bb = ((const float4*)bias)[c4];
        bf16x4 o;
        o[0] = (__bf16)fmaxf(v.x + bb.x, 0.f);
        o[1] = (__bf16)fmaxf(v.y + bb.y, 0.f);
        o[2] = (__bf16)fmaxf(v.z + bb.z, 0.f);
        o[3] = (__bf16)fmaxf(v.w + bb.w, 0.f);
        ((bf16x4*)msg)[i] = o;
    }
}

// ---------------- fp32 -> bf16 weight convert ----------------
__global__ void conv_kernel(const float* __restrict__ src, __bf16* __restrict__ dst, int n4) {
    int i = blockIdx.x * blockDim.x + threadIdx.x;
    if (i < n4) {
        float4 v = ((const float4*)src)[i];
        bf16x4 o;
        o[0] = (__bf16)v.x; o[1] = (__bf16)v.y; o[2] = (__bf16)v.z; o[3] = (__bf16)v.w;
        ((bf16x4*)dst)[i] = o;
    }
}

// ---------------- gx = msg @ w_ih^T  (NT GEMM, bf16 out) ----------------
// v2: 32-row blocks (alds 32KB + tile 8.5KB = 41.5KB) -> 3 blocks/CU, 3 waves/SIMD.
// The inner-loop B loads are L2-served (~250cy); at R12's 1 block/CU (1 wave/SIMD)
// the kernel was latency-bound (~330us vs ~50us roofline). 3x TLP hides it.
__global__ __launch_bounds__(256) void gx_gemm(const __bf16* __restrict__ msg,
                                               const __bf16* __restrict__ wih,  // [2][1536][512]
                                               __bf16* __restrict__ gx,         // [2][N][1536]
                                               int N) {
    __shared__ __bf16 alds[32 * 512];    // 32KB, rows of 1KB, 16B-chunk XOR swizzle
    __shared__ __bf16 tile[32][136];     // 8.5KB output repack
    int dir = blockIdx.y;
    int r0 = blockIdx.x * 32;
    int wid = threadIdx.x >> 6, lane = threadIdx.x & 63;
    int lrow = lane & 15, lk = lane >> 4;
    const __bf16* wB = wih + (size_t)dir * H3 * HID;
    __bf16* gOut = gx + (size_t)dir * N * H3;

    // stage A (32 rows x 512 K) with swizzled 16B chunks
    for (int i = threadIdx.x; i < 32 * 64; i += 256) {
        int row = i >> 6, ch = i & 63;
        int sch = ch ^ (row & 7);
        int grow = r0 + row; if (grow >= N) grow = N - 1;
        *(bf16x8*)(&alds[row * 512 + sch * 8]) = *(const bf16x8*)(msg + (size_t)grow * HID + ch * 8);
    }
    __syncthreads();

    for (int ct = 0; ct < 12; ++ct) {
        int c0 = ct * 128 + wid * 32;    // this wave's 32 output cols
        f32x4 acc[2][2] = {};            // 2 row-frags x 2 col-frags
#pragma unroll
        for (int ks = 0; ks < 16; ++ks) {
            bf16x8 b0 = *(const bf16x8*)(wB + (size_t)(c0 + lrow) * HID + ks * 32 + lk * 8);
            bf16x8 b1 = *(const bf16x8*)(wB + (size_t)(c0 + 16 + lrow) * HID + ks * 32 + lk * 8);
#pragma unroll
            for (int rf = 0; rf < 2; ++rf) {
                int row = rf * 16 + lrow;
                int sch = (ks * 4 + lk) ^ (row & 7);
                bf16x8 av = *(const bf16x8*)(&alds[row * 512 + sch * 8]);
                acc[rf][0] = __builtin_amdgcn_mfma_f32_16x16x32_bf16(av, b0, acc[rf][0], 0, 0, 0);
                acc[rf][1] = __builtin_amdgcn_mfma_f32_16x16x32_bf16(av, b1, acc[rf][1], 0, 0, 0);
            }
        }
        __syncthreads();   // tile free from previous ct's readers
#pragma unroll
        for (int rf = 0; rf < 2; ++rf)
#pragma unroll
            for (int fj = 0; fj < 2; ++fj)
#pragma unroll
                for (int r = 0; r < 4; ++r)
                    tile[rf * 16 + (lane >> 4) * 4 + r][wid * 32 + fj * 16 + (lane & 15)] =
                        (__bf16)acc[rf][fj][r];
        __syncthreads();
        // threads 0..127 = 32 rows x 4 chunks of 32 cols; each writes all 32 cols
        if (threadIdx.x < 128) {
            int row = threadIdx.x >> 2, ch = threadIdx.x & 3;
            if (r0 + row < N) {
                __bf16* d = gOut + (size_t)(r0 + row) * H3 + ct * 128 + ch * 32;
                *(bf16x8*)(d)      = *(const bf16x8*)(&tile[row][ch * 32]);
                *(bf16x8*)(d + 8)  = *(const bf16x8*)(&tile[row][ch * 32 + 8]);
                *(bf16x8*)(d + 16) = *(const bf16x8*)(&tile[row][ch * 32 + 16]);
                *(bf16x8*)(d + 24) = *(const bf16x8*)(&tile[row][ch * 32 + 24]);
            }
        }
    }
}

// ================= persistent GRU scan — PER-WAVE flags & exchange (R12, frozen) =================
__global__ __launch_bounds__(256, 1) void gru_scan(
    const __bf16* __restrict__ whh,   // [2][1536][512]
    const __bf16* __restrict__ gx,    // [2][N][1536]
    const float* __restrict__ h0,     // [B][H]
    __bf16* __restrict__ hb,          // [2 bufs][2 dirs][B][H]
    const float* __restrict__ b_ih_f, const float* __restrict__ b_hh_f,
    const float* __restrict__ b_ih_b, const float* __restrict__ b_hh_b,
    const int* __restrict__ len, const int* __restrict__ starts,
    unsigned* __restrict__ ctr,       // [16 grp][4 wid][16 hc] u32 = 4KB
    float* __restrict__ out, int N) {

    __shared__ __bf16 wlds[96 * 512];    // 96KB W tile, 16B-chunk XOR swizzle
    __shared__ __bf16 hout[4][16 * 40];  // per-wave private repack (no cross-wave sync)

    int bid = blockIdx.x;
    int rg  = bid & 7;
    int dir = (bid >> 3) & 1;
    int hc  = bid >> 4;
    int grp = dir * 8 + rg;
    int wid = threadIdx.x >> 6, lane = threadIdx.x & 63;
    int r0 = rg * 64;
    int c0 = hc * 32;

    for (int i = threadIdx.x; i < 96 * 64; i += 256) {
        int row = i >> 6, ch = i & 63;
        int g = row >> 5, c = row & 31;
        int sch = ch ^ (row & 7);
        const __bf16* src = whh + ((size_t)dir * H3 + (size_t)g * HID + c0 + c) * HID + ch * 8;
        *(bf16x8*)(&wlds[row * 512 + sch * 8]) = *(const bf16x8*)src;
    }

    int wr0 = r0 + wid * 16;
    int lrow = lane & 15;
    int lk   = lane >> 4;

    int mycol[2], myrow[4];
#pragma unroll
    for (int fj = 0; fj < 2; ++fj) mycol[fj] = c0 + fj * 16 + (lane & 15);
#pragma unroll
    for (int r = 0; r < 4; ++r) myrow[r] = wr0 + (lane >> 4) * 4 + r;

    float hreg[2][4], sreg[2][4];
#pragma unroll
    for (int fj = 0; fj < 2; ++fj)
#pragma unroll
        for (int r = 0; r < 4; ++r) {
            hreg[fj][r] = h0[(size_t)myrow[r] * HID + mycol[fj]];
            sreg[fj][r] = 0.f;
        }

    const float* bih = dir ? b_ih_b : b_ih_f;
    const float* bhh = dir ? b_hh_b : b_hh_f;
    float bihv[2][3], bhhv[2][3];
#pragma unroll
    for (int fj = 0; fj < 2; ++fj)
#pragma unroll
        for (int g = 0; g < 3; ++g) {
            bihv[fj][g] = bih[g * HID + mycol[fj]];
            bhhv[fj][g] = bhh[g * HID + mycol[fj]];
        }
    int mylen[4], mystart[4];
#pragma unroll
    for (int r = 0; r < 4; ++r) { mylen[r] = len[myrow[r]]; mystart[r] = starts[myrow[r]]; }

    // gx prefetch for step 0
    float gxv[2][4][3];
    {
        int t = dir ? (MAXL - 1) : 0;
#pragma unroll
        for (int r = 0; r < 4; ++r) {
            bool real = t < mylen[r];
            size_t base = ((size_t)dir * N + mystart[r] + t) * H3;
#pragma unroll
            for (int fj = 0; fj < 2; ++fj)
#pragma unroll
                for (int g = 0; g < 3; ++g)
                    gxv[fj][r][g] = real ? (float)gx[base + (size_t)g * HID + mycol[fj]] : 0.f;
        }
    }

    __syncthreads();   // wlds ready — only block-wide sync in this kernel

    const size_t bufStride = (size_t)2 * BATCH * HID;
    const size_t stoff = (size_t)(wr0 + (lane >> 2)) * HID + c0 + (lane & 3) * 8;
    unsigned* myArrive = ctr + grp * 64 + wid * 16 + hc;
    const unsigned* myPoll = ctr + grp * 64 + wid * 16 + (lane & 15);

    for (int s = 0; s < MAXL; ++s) {
        int t = dir ? (MAXL - 1 - s) : s;
        const __bf16* hcur = hb + (size_t)(s & 1) * bufStride + (size_t)dir * BATCH * HID;
        __bf16* hnxt = hb + (size_t)((s + 1) & 1) * bufStride + (size_t)dir * BATCH * HID;

        // ---- A: this wave's [16 rows x 512 K] via coherent 16B loads, all in flight
        bf16x8 a[16];
#pragma unroll
        for (int ks = 0; ks < 16; ++ks)
            a[ks] = ld_coh16(hcur + (size_t)(wr0 + lrow) * HID + ks * 32 + lk * 8);
        asm volatile("s_waitcnt vmcnt(0)" ::: "memory");
        __builtin_amdgcn_sched_barrier(0);   // keep MFMAs below the waitcnt (rule 18)

        // ---- GEMM: gh = h @ whh^T, 3 gates x 2 col-frags
        f32x4 acc[3][2] = {};
#pragma unroll
        for (int ks = 0; ks < 16; ++ks) {
#pragma unroll
            for (int g = 0; g < 3; ++g) {
#pragma unroll
                for (int f = 0; f < 2; ++f) {
                    int row = g * 32 + f * 16 + lrow;
                    int sch = (ks * 4 + lk) ^ (row & 7);
                    bf16x8 b = *(const bf16x8*)(&wlds[row * 512 + sch * 8]);
                    acc[g][f] = __builtin_amdgcn_mfma_f32_16x16x32_bf16(a[ks], b, acc[g][f], 0, 0, 0);
                }
            }
        }

        // ---- gate math + state update (fp32, registers)
#pragma unroll
        for (int fj = 0; fj < 2; ++fj)
#pragma unroll
            for (int r = 0; r < 4; ++r) {
                float ghr = acc[0][fj][r] + bhhv[fj][0];
                float ghz = acc[1][fj][r] + bhhv[fj][1];
                float ghn = acc[2][fj][r] + bhhv[fj][2];
                float xr = gxv[fj][r][0] + bihv[fj][0];
                float xz = gxv[fj][r][1] + bihv[fj][1];
                float xn = gxv[fj][r][2] + bihv[fj][2];
                float rg_ = 1.f / (1.f + expf(-(xr + ghr)));
                float zg  = 1.f / (1.f + expf(-(xz + ghz)));
                float ng  = tanhf(xn + rg_ * ghn);
                float hn  = (1.f - zg) * ng + zg * hreg[fj][r];
                hreg[fj][r] = hn;
                if (t < mylen[r]) sreg[fj][r] += hn;
            }

        if (s + 1 == MAXL) break;   // no exchange after last step

        // ---- per-wave repack (wave-internal LDS ordering) + per-wave 16B stores
#pragma unroll
        for (int fj = 0; fj < 2; ++fj)
#pragma unroll
            for (int r = 0; r < 4; ++r)
                hout[wid][(lk * 4 + r) * 40 + fj * 16 + lrow] = (__bf16)hreg[fj][r];
        {
            bf16x8 v = *(const bf16x8*)(&hout[wid][(lane >> 2) * 40 + (lane & 3) * 8]);
            st_coh16(hnxt + stoff, v);
        }
        // drain THIS WAVE's store (per-wave vmcnt), then arrive on own slot
        asm volatile("s_waitcnt vmcnt(0)" ::: "memory");
        if (lane == 0) st_coh4(myArrive, (unsigned)(s + 1));

        // gx prefetch for step s+1 — flies under the poll
        {
            int tn = dir ? (MAXL - 2 - s) : (s + 1);
#pragma unroll
            for (int r = 0; r < 4; ++r) {
                bool real = tn < mylen[r];
                size_t base = ((size_t)dir * N + mystart[r] + tn) * H3;
#pragma unroll
                for (int fj = 0; fj < 2; ++fj)
#pragma unroll
                    for (int g = 0; g < 3; ++g)
                        gxv[fj][r][g] = real ? (float)gx[base + (size_t)g * HID + mycol[fj]] : 0.f;
            }
        }

        // ---- poll: all lanes watch the 16 same-wid slots (one 64B line)
        {
            unsigned tgt = (unsigned)(s + 1);
            for (;;) {
                unsigned v = ld_coh4(myPoll);
                if (__ballot(v < tgt) == 0ull) break;
                __builtin_amdgcn_s_sleep(1);
            }
        }
        asm volatile("" ::: "memory");       // no compiler motion across the spin exit
        __builtin_amdgcn_sched_barrier(0);   // keep next A-loads after it
    }

    // ---- final output: out[row][dir*H + col] = sum / len
#pragma unroll
    for (int fj = 0; fj < 2; ++fj)
#pragma unroll
        for (int r = 0; r < 4; ++r)
            out[(size_t)myrow[r] * (2 * HID) + (size_t)dir * HID + mycol[fj]] =
                sreg[fj][r] / (float)mylen[r];
}

extern "C" void kernel_launch(void* const* d_in, const int* in_sizes, int n_in,
                              void* d_out, int out_size, void* d_ws, size_t ws_size,
                              hipStream_t stream) {
    const float* h      = (const float*)d_in[0];
    const int*   lens   = (const int*)d_in[1];
    const float* bias   = (const float*)d_in[2];
    const float* w_ih_f = (const float*)d_in[3];
    const float* w_hh_f = (const float*)d_in[4];
    const float* b_ih_f = (const float*)d_in[5];
    const float* b_hh_f = (const float*)d_in[6];
    const float* w_ih_b = (const float*)d_in[7];
    const float* w_hh_b = (const float*)d_in[8];
    const float* b_ih_b = (const float*)d_in[9];
    const float* b_hh_b = (const float*)d_in[10];
    float* out = (float*)d_out;
    const int N = in_sizes[0] / HID;

    // workspace layout — identical to the R12 passing layout
    char* p = (char*)d_ws;
    size_t off = 0;
    int* starts   = (int*)(p + off);        off += 4096;
    unsigned* ctr = (unsigned*)(p + off);   off += 4096;   // 1024 u32 flag slots
    float* h0   = (float*)(p + off);        off += (size_t)BATCH * HID * 4;
    __bf16* hb  = (__bf16*)(p + off);       off += (size_t)2 * 2 * BATCH * HID * 2;
    __bf16* wih = (__bf16*)(p + off);       off += (size_t)2 * H3 * HID * 2;
    __bf16* whh = (__bf16*)(p + off);       off += (size_t)2 * H3 * HID * 2;
    __bf16* msg = (__bf16*)(p + off);       off += (size_t)N * HID * 2;
    __bf16* gx  = (__bf16*)(p + off);       off += (size_t)2 * N * H3 * 2;
    if (off > ws_size) return;  // interpretable failure: output stays zero

    scan_kernel<<<1, BATCH, 0, stream>>>(lens, starts, ctr);
    init_kernel<<<BATCH, HID, 0, stream>>>(h, lens, starts, h0, hb);

    long total4 = (long)N * HID / 4;
    int msgBlocks = (int)((total4 + 255) / 256); if (msgBlocks > 2048) msgBlocks = 2048;
    msg_kernel<<<msgBlocks, 256, 0, stream>>>(h, bias, msg, total4);

    int n4 = H3 * HID / 4;
    int cb = (n4 + 255) / 256;
    conv_kernel<<<cb, 256, 0, stream>>>(w_ih_f, wih, n4);
    conv_kernel<<<cb, 256, 0, stream>>>(w_ih_b, wih + (size_t)H3 * HID, n4);
    conv_kernel<<<cb, 256, 0, stream>>>(w_hh_f, whh, n4);
    conv_kernel<<<cb, 256, 0, stream>>>(w_hh_b, whh + (size_t)H3 * HID, n4);

    gx_gemm<<<dim3((N + 31) / 32, 2), 256, 0, stream>>>(msg, wih, gx, N);

    int Nv = N;
    void* kargs[] = {(void*)&whh, (void*)&gx, (void*)&h0, (void*)&hb,
                     (void*)&b_ih_f, (void*)&b_hh_f, (void*)&b_ih_b, (void*)&b_hh_b,
                     (void*)&lens, (void*)&starts, (void*)&ctr, (void*)&out, (void*)&Nv};
    hipLaunchCooperativeKernel((const void*)gru_scan, dim3(256), dim3(256), kargs, 0, stream);
}

// Round 15
// 1729.159 us; speedup vs baseline: 1.4391x; 1.0732x over previous
//
#include <hip/hip_runtime.h>
#include <hip/hip_bf16.h>
#include <math.h>

#define BATCH 512
#define MAXL 128
#define HID 512
#define H3 1536

typedef __bf16 bf16x8 __attribute__((ext_vector_type(8)));
typedef __bf16 bf16x4 __attribute__((ext_vector_type(4)));
typedef float f32x4 __attribute__((ext_vector_type(4)));

// Device-coherent (MALL meeting point) ops — proven R6/R7/R12 path. sc0 sc1 bypasses
// stale L1/L2; always correct cross-XCD.
__device__ __forceinline__ bf16x8 ld_coh16(const __bf16* p) {
    bf16x8 v;
    asm volatile("global_load_dwordx4 %0, %1, off sc0 sc1"
                 : "=v"(v) : "v"((const void*)p) : "memory");
    return v;
}
__device__ __forceinline__ void st_coh16(__bf16* p, bf16x8 v) {
    asm volatile("global_store_dwordx4 %0, %1, off sc0 sc1"
                 :: "v"((void*)p), "v"(v) : "memory");
}
__device__ __forceinline__ void st_coh4(unsigned* p, unsigned v) {
    asm volatile("global_store_dword %0, %1, off sc0 sc1"
                 :: "v"((void*)p), "v"(v) : "memory");
}
__device__ __forceinline__ unsigned ld_coh4(const unsigned* p) {
    unsigned v;
    asm volatile("global_load_dword %0, %1, off sc0 sc1"
                 : "=v"(v) : "v"((const void*)p) : "memory");
    asm volatile("s_waitcnt vmcnt(0)" ::: "memory");
    return v;
}

// ---------------- prefix scan of lengths -> starts; zero barrier slots ----------------
__global__ __launch_bounds__(BATCH) void scan_kernel(const int* __restrict__ len,
                                                     int* __restrict__ starts,
                                                     unsigned* __restrict__ ctr) {
    __shared__ int buf[BATCH];
    int tid = threadIdx.x;
    ctr[tid] = 0u;                    // 1024 slots: [16 grp][4 wid][16 hc]
    ctr[tid + BATCH] = 0u;            // re-zeroed every launch (graph-replay determinism)
    int myLen = len[tid];
    buf[tid] = myLen;
    __syncthreads();
    for (int off = 1; off < BATCH; off <<= 1) {
        int v = (tid >= off) ? buf[tid - off] : 0;
        __syncthreads();
        buf[tid] += v;
        __syncthreads();
    }
    starts[tid] = buf[tid] - myLen;   // exclusive scan
}

// ------- h0 = segment_max(h) (fp32 + bf16 into scan buffer 0, both dirs) -------
// v2: 4-way unrolled accumulators — break the serial load+fmax chain (ILP).
__global__ __launch_bounds__(HID) void init_kernel(const float* __restrict__ h,
                                                   const int* __restrict__ len,
                                                   const int* __restrict__ starts,
                                                   float* __restrict__ h0,     // [B][H]
                                                   __bf16* __restrict__ hb) {  // buf0: [2][B][H]
    int b = blockIdx.x, j = threadIdx.x;
    int s = starts[b], L = len[b];
    const float* hp = h + (size_t)s * HID + j;
    float m0 = -3.4e38f, m1 = -3.4e38f, m2 = -3.4e38f, m3 = -3.4e38f;
    int t = 0;
    for (; t + 3 < L; t += 4) {
        m0 = fmaxf(m0, hp[(size_t)(t + 0) * HID]);
        m1 = fmaxf(m1, hp[(size_t)(t + 1) * HID]);
        m2 = fmaxf(m2, hp[(size_t)(t + 2) * HID]);
        m3 = fmaxf(m3, hp[(size_t)(t + 3) * HID]);
    }
    for (; t < L; ++t) m0 = fmaxf(m0, hp[(size_t)t * HID]);
    float m = fmaxf(fmaxf(m0, m1), fmaxf(m2, m3));
    h0[(size_t)b * HID + j] = m;
    hb[(size_t)b * HID + j] = (__bf16)m;
    hb[(size_t)(BATCH + b) * HID + j] = (__bf16)m;
}

// ---------------- message = relu(h + bias) -> bf16 ----------------
__global__ void msg_kernel(const float* __restrict__ h, const float* __restrict__ bias,
                           __bf16* __restrict__ msg, long total4) {
    for (long i = (long)blockIdx.x * blockDim.x + threadIdx.x; i < total4;
         i += (long)gridDim.x * blockDim.x) {
        float4 v = ((const float4*)h)[i];
        int c4 = (int)(i & (HID / 4 - 1));
        float4 bb = ((const float4*)bias)[c4];
        bf16x4 o;
        o[0] = (__bf16)fmaxf(v.x + bb.x, 0.f);
        o[1] = (__bf16)fmaxf(v.y + bb.y, 0.f);
        o[2] = (__bf16)fmaxf(v.z + bb.z, 0.f);
        o[3] = (__bf16)fmaxf(v.w + bb.w, 0.f);
        ((bf16x4*)msg)[i] = o;
    }
}

// ---------------- fp32 -> bf16 weight convert ----------------
__global__ void conv_kernel(const float* __restrict__ src, __bf16* __restrict__ dst, int n4) {
    int i = blockIdx.x * blockDim.x + threadIdx.x;
    if (i < n4) {
        float4 v = ((const float4*)src)[i];
        bf16x4 o;
        o[0] = (__bf16)v.x; o[1] = (__bf16)v.y; o[2] = (__bf16)v.z; o[3] = (__bf16)v.w;
        ((bf16x4*)dst)[i] = o;
    }
}

// ---------------- gx = msg @ w_ih^T  (NT GEMM, bf16 out) ----------------
// v3: 64-row tiles (B-traffic 1.56GB, half of v2) + per-wave private repack
// (5KB, the gru_scan hout pattern) instead of the 17KB block tile ->
// alds 64KB + 5KB = 69KB -> 2 blocks/CU, 2 waves/SIMD hide the L2 latency
// that bound the R12 version (1 wave/SIMD, ~330us vs ~90us L2-BW floor).
__global__ __launch_bounds__(256) void gx_gemm(const __bf16* __restrict__ msg,
                                               const __bf16* __restrict__ wih,  // [2][1536][512]
                                               __bf16* __restrict__ gx,         // [2][N][1536]
                                               int N) {
    __shared__ __bf16 alds[64 * 512];    // 64KB, rows of 1KB, 16B-chunk XOR swizzle
    __shared__ __bf16 ctile[4][16 * 40]; // 5KB: per-wave private C repack
    int dir = blockIdx.y;
    int r0 = blockIdx.x * 64;
    int wid = threadIdx.x >> 6, lane = threadIdx.x & 63;
    int lrow = lane & 15, lk = lane >> 4;
    const __bf16* wB = wih + (size_t)dir * H3 * HID;
    __bf16* gOut = gx + (size_t)dir * N * H3;

    // stage A (64 rows x 512 K) with swizzled 16B chunks
    for (int i = threadIdx.x; i < 64 * 64; i += 256) {
        int row = i >> 6, ch = i & 63;
        int sch = ch ^ (row & 7);
        int grow = r0 + row; if (grow >= N) grow = N - 1;
        *(bf16x8*)(&alds[row * 512 + sch * 8]) = *(const bf16x8*)(msg + (size_t)grow * HID + ch * 8);
    }
    __syncthreads();

    for (int ct = 0; ct < 12; ++ct) {
        int c0 = ct * 128 + wid * 32;    // this wave's 32 output cols
        f32x4 acc[4][2] = {};            // 4 row-frags x 2 col-frags
#pragma unroll
        for (int ks = 0; ks < 16; ++ks) {
            bf16x8 b0 = *(const bf16x8*)(wB + (size_t)(c0 + lrow) * HID + ks * 32 + lk * 8);
            bf16x8 b1 = *(const bf16x8*)(wB + (size_t)(c0 + 16 + lrow) * HID + ks * 32 + lk * 8);
#pragma unroll
            for (int rf = 0; rf < 4; ++rf) {
                int row = rf * 16 + lrow;
                int sch = (ks * 4 + lk) ^ (row & 7);
                bf16x8 av = *(const bf16x8*)(&alds[row * 512 + sch * 8]);
                acc[rf][0] = __builtin_amdgcn_mfma_f32_16x16x32_bf16(av, b0, acc[rf][0], 0, 0, 0);
                acc[rf][1] = __builtin_amdgcn_mfma_f32_16x16x32_bf16(av, b1, acc[rf][1], 0, 0, 0);
            }
        }
        // per-wave private repack + coalesced 16B stores (hout pattern from gru_scan)
#pragma unroll
        for (int rf = 0; rf < 4; ++rf) {
#pragma unroll
            for (int fj = 0; fj < 2; ++fj)
#pragma unroll
                for (int r = 0; r < 4; ++r)
                    ctile[wid][(lk * 4 + r) * 40 + fj * 16 + lrow] = (__bf16)acc[rf][fj][r];
            asm volatile("s_waitcnt lgkmcnt(0)" ::: "memory");   // cross-lane LDS fence
            int row = r0 + rf * 16 + (lane >> 2);
            if (row < N) {
                bf16x8 v = *(const bf16x8*)(&ctile[wid][(lane >> 2) * 40 + (lane & 3) * 8]);
                *(bf16x8*)(gOut + (size_t)row * H3 + c0 + (lane & 3) * 8) = v;
            }
            asm volatile("s_waitcnt lgkmcnt(0)" ::: "memory");   // reads done before reuse
        }
    }
}

// ================= persistent GRU scan — PER-WAVE flags & exchange (R12, frozen) =================
__global__ __launch_bounds__(256, 1) void gru_scan(
    const __bf16* __restrict__ whh,   // [2][1536][512]
    const __bf16* __restrict__ gx,    // [2][N][1536]
    const float* __restrict__ h0,     // [B][H]
    __bf16* __restrict__ hb,          // [2 bufs][2 dirs][B][H]
    const float* __restrict__ b_ih_f, const float* __restrict__ b_hh_f,
    const float* __restrict__ b_ih_b, const float* __restrict__ b_hh_b,
    const int* __restrict__ len, const int* __restrict__ starts,
    unsigned* __restrict__ ctr,       // [16 grp][4 wid][16 hc] u32 = 4KB
    float* __restrict__ out, int N) {

    __shared__ __bf16 wlds[96 * 512];    // 96KB W tile, 16B-chunk XOR swizzle
    __shared__ __bf16 hout[4][16 * 40];  // per-wave private repack (no cross-wave sync)

    int bid = blockIdx.x;
    int rg  = bid & 7;
    int dir = (bid >> 3) & 1;
    int hc  = bid >> 4;
    int grp = dir * 8 + rg;
    int wid = threadIdx.x >> 6, lane = threadIdx.x & 63;
    int r0 = rg * 64;
    int c0 = hc * 32;

    for (int i = threadIdx.x; i < 96 * 64; i += 256) {
        int row = i >> 6, ch = i & 63;
        int g = row >> 5, c = row & 31;
        int sch = ch ^ (row & 7);
        const __bf16* src = whh + ((size_t)dir * H3 + (size_t)g * HID + c0 + c) * HID + ch * 8;
        *(bf16x8*)(&wlds[row * 512 + sch * 8]) = *(const bf16x8*)src;
    }

    int wr0 = r0 + wid * 16;
    int lrow = lane & 15;
    int lk   = lane >> 4;

    int mycol[2], myrow[4];
#pragma unroll
    for (int fj = 0; fj < 2; ++fj) mycol[fj] = c0 + fj * 16 + (lane & 15);
#pragma unroll
    for (int r = 0; r < 4; ++r) myrow[r] = wr0 + (lane >> 4) * 4 + r;

    float hreg[2][4], sreg[2][4];
#pragma unroll
    for (int fj = 0; fj < 2; ++fj)
#pragma unroll
        for (int r = 0; r < 4; ++r) {
            hreg[fj][r] = h0[(size_t)myrow[r] * HID + mycol[fj]];
            sreg[fj][r] = 0.f;
        }

    const float* bih = dir ? b_ih_b : b_ih_f;
    const float* bhh = dir ? b_hh_b : b_hh_f;
    float bihv[2][3], bhhv[2][3];
#pragma unroll
    for (int fj = 0; fj < 2; ++fj)
#pragma unroll
        for (int g = 0; g < 3; ++g) {
            bihv[fj][g] = bih[g * HID + mycol[fj]];
            bhhv[fj][g] = bhh[g * HID + mycol[fj]];
        }
    int mylen[4], mystart[4];
#pragma unroll
    for (int r = 0; r < 4; ++r) { mylen[r] = len[myrow[r]]; mystart[r] = starts[myrow[r]]; }

    // gx prefetch for step 0
    float gxv[2][4][3];
    {
        int t = dir ? (MAXL - 1) : 0;
#pragma unroll
        for (int r = 0; r < 4; ++r) {
            bool real = t < mylen[r];
            size_t base = ((size_t)dir * N + mystart[r] + t) * H3;
#pragma unroll
            for (int fj = 0; fj < 2; ++fj)
#pragma unroll
                for (int g = 0; g < 3; ++g)
                    gxv[fj][r][g] = real ? (float)gx[base + (size_t)g * HID + mycol[fj]] : 0.f;
        }
    }

    __syncthreads();   // wlds ready — only block-wide sync in this kernel

    const size_t bufStride = (size_t)2 * BATCH * HID;
    const size_t stoff = (size_t)(wr0 + (lane >> 2)) * HID + c0 + (lane & 3) * 8;
    unsigned* myArrive = ctr + grp * 64 + wid * 16 + hc;
    const unsigned* myPoll = ctr + grp * 64 + wid * 16 + (lane & 15);

    for (int s = 0; s < MAXL; ++s) {
        int t = dir ? (MAXL - 1 - s) : s;
        const __bf16* hcur = hb + (size_t)(s & 1) * bufStride + (size_t)dir * BATCH * HID;
        __bf16* hnxt = hb + (size_t)((s + 1) & 1) * bufStride + (size_t)dir * BATCH * HID;

        // ---- A: this wave's [16 rows x 512 K] via coherent 16B loads, all in flight
        bf16x8 a[16];
#pragma unroll
        for (int ks = 0; ks < 16; ++ks)
            a[ks] = ld_coh16(hcur + (size_t)(wr0 + lrow) * HID + ks * 32 + lk * 8);
        asm volatile("s_waitcnt vmcnt(0)" ::: "memory");
        __builtin_amdgcn_sched_barrier(0);   // keep MFMAs below the waitcnt (rule 18)

        // ---- GEMM: gh = h @ whh^T, 3 gates x 2 col-frags
        f32x4 acc[3][2] = {};
#pragma unroll
        for (int ks = 0; ks < 16; ++ks) {
#pragma unroll
            for (int g = 0; g < 3; ++g) {
#pragma unroll
                for (int f = 0; f < 2; ++f) {
                    int row = g * 32 + f * 16 + lrow;
                    int sch = (ks * 4 + lk) ^ (row & 7);
                    bf16x8 b = *(const bf16x8*)(&wlds[row * 512 + sch * 8]);
                    acc[g][f] = __builtin_amdgcn_mfma_f32_16x16x32_bf16(a[ks], b, acc[g][f], 0, 0, 0);
                }
            }
        }

        // ---- gate math + state update (fp32, registers)
#pragma unroll
        for (int fj = 0; fj < 2; ++fj)
#pragma unroll
            for (int r = 0; r < 4; ++r) {
                float ghr = acc[0][fj][r] + bhhv[fj][0];
                float ghz = acc[1][fj][r] + bhhv[fj][1];
                float ghn = acc[2][fj][r] + bhhv[fj][2];
                float xr = gxv[fj][r][0] + bihv[fj][0];
                float xz = gxv[fj][r][1] + bihv[fj][1];
                float xn = gxv[fj][r][2] + bihv[fj][2];
                float rg_ = 1.f / (1.f + expf(-(xr + ghr)));
                float zg  = 1.f / (1.f + expf(-(xz + ghz)));
                float ng  = tanhf(xn + rg_ * ghn);
                float hn  = (1.f - zg) * ng + zg * hreg[fj][r];
                hreg[fj][r] = hn;
                if (t < mylen[r]) sreg[fj][r] += hn;
            }

        if (s + 1 == MAXL) break;   // no exchange after last step

        // ---- per-wave repack (wave-internal LDS ordering) + per-wave 16B stores
#pragma unroll
        for (int fj = 0; fj < 2; ++fj)
#pragma unroll
            for (int r = 0; r < 4; ++r)
                hout[wid][(lk * 4 + r) * 40 + fj * 16 + lrow] = (__bf16)hreg[fj][r];
        {
            bf16x8 v = *(const bf16x8*)(&hout[wid][(lane >> 2) * 40 + (lane & 3) * 8]);
            st_coh16(hnxt + stoff, v);
        }
        // drain THIS WAVE's store (per-wave vmcnt), then arrive on own slot
        asm volatile("s_waitcnt vmcnt(0)" ::: "memory");
        if (lane == 0) st_coh4(myArrive, (unsigned)(s + 1));

        // gx prefetch for step s+1 — flies under the poll
        {
            int tn = dir ? (MAXL - 2 - s) : (s + 1);
#pragma unroll
            for (int r = 0; r < 4; ++r) {
                bool real = tn < mylen[r];
                size_t base = ((size_t)dir * N + mystart[r] + tn) * H3;
#pragma unroll
                for (int fj = 0; fj < 2; ++fj)
#pragma unroll
                    for (int g = 0; g < 3; ++g)
                        gxv[fj][r][g] = real ? (float)gx[base + (size_t)g * HID + mycol[fj]] : 0.f;
            }
        }

        // ---- poll: all lanes watch the 16 same-wid slots (one 64B line)
        {
            unsigned tgt = (unsigned)(s + 1);
            for (;;) {
                unsigned v = ld_coh4(myPoll);
                if (__ballot(v < tgt) == 0ull) break;
                __builtin_amdgcn_s_sleep(1);
            }
        }
        asm volatile("" ::: "memory");       // no compiler motion across the spin exit
        __builtin_amdgcn_sched_barrier(0);   // keep next A-loads after it
    }

    // ---- final output: out[row][dir*H + col] = sum / len
#pragma unroll
    for (int fj = 0; fj < 2; ++fj)
#pragma unroll
        for (int r = 0; r < 4; ++r)
            out[(size_t)myrow[r] * (2 * HID) + (size_t)dir * HID + mycol[fj]] =
                sreg[fj][r] / (float)mylen[r];
}

extern "C" void kernel_launch(void* const* d_in, const int* in_sizes, int n_in,
                              void* d_out, int out_size, void* d_ws, size_t ws_size,
                              hipStream_t stream) {
    const float* h      = (const float*)d_in[0];
    const int*   lens   = (const int*)d_in[1];
    const float* bias   = (const float*)d_in[2];
    const float* w_ih_f = (const float*)d_in[3];
    const float* w_hh_f = (const float*)d_in[4];
    const float* b_ih_f = (const float*)d_in[5];
    const float* b_hh_f = (const float*)d_in[6];
    const float* w_ih_b = (const float*)d_in[7];
    const float* w_hh_b = (const float*)d_in[8];
    const float* b_ih_b = (const float*)d_in[9];
    const float* b_hh_b = (const float*)d_in[10];
    float* out = (float*)d_out;
    const int N = in_sizes[0] / HID;

    // workspace layout — identical to the R12 passing layout
    char* p = (char*)d_ws;
    size_t off = 0;
    int* starts   = (int*)(p + off);        off += 4096;
    unsigned* ctr = (unsigned*)(p + off);   off += 4096;   // 1024 u32 flag slots
    float* h0   = (float*)(p + off);        off += (size_t)BATCH * HID * 4;
    __bf16* hb  = (__bf16*)(p + off);       off += (size_t)2 * 2 * BATCH * HID * 2;
    __bf16* wih = (__bf16*)(p + off);       off += (size_t)2 * H3 * HID * 2;
    __bf16* whh = (__bf16*)(p + off);       off += (size_t)2 * H3 * HID * 2;
    __bf16* msg = (__bf16*)(p + off);       off += (size_t)N * HID * 2;
    __bf16* gx  = (__bf16*)(p + off);       off += (size_t)2 * N * H3 * 2;
    if (off > ws_size) return;  // interpretable failure: output stays zero

    scan_kernel<<<1, BATCH, 0, stream>>>(lens, starts, ctr);
    init_kernel<<<BATCH, HID, 0, stream>>>(h, lens, starts, h0, hb);

    long total4 = (long)N * HID / 4;
    int msgBlocks = (int)((total4 + 255) / 256); if (msgBlocks > 2048) msgBlocks = 2048;
    msg_kernel<<<msgBlocks, 256, 0, stream>>>(h, bias, msg, total4);

    int n4 = H3 * HID / 4;
    int cb = (n4 + 255) / 256;
    conv_kernel<<<cb, 256, 0, stream>>>(w_ih_f, wih, n4);
    conv_kernel<<<cb, 256, 0, stream>>>(w_ih_b, wih + (size_t)H3 * HID, n4);
    conv_kernel<<<cb, 256, 0, stream>>>(w_hh_f, whh, n4);
    conv_kernel<<<cb, 256, 0, stream>>>(w_hh_b, whh + (size_t)H3 * HID, n4);

    gx_gemm<<<dim3((N + 63) / 64, 2), 256, 0, stream>>>(msg, wih, gx, N);

    int Nv = N;
    void* kargs[] = {(void*)&whh, (void*)&gx, (void*)&h0, (void*)&hb,
                     (void*)&b_ih_f, (void*)&b_hh_f, (void*)&b_ih_b, (void*)&b_hh_b,
                     (void*)&lens, (void*)&starts, (void*)&ctr, (void*)&out, (void*)&Nv};
    hipLaunchCooperativeKernel((const void*)gru_scan, dim3(256), dim3(256), kargs, 0, stream);
}

// Round 16
// 1555.128 us; speedup vs baseline: 1.6001x; 1.1119x over previous
//
#include <hip/hip_runtime.h>
#include <hip/hip_bf16.h>
#include <math.h>

#define BATCH 512
#define MAXL 128
#define HID 512
#define H3 1536

typedef __bf16 bf16x8 __attribute__((ext_vector_type(8)));
typedef __bf16 bf16x4 __attribute__((ext_vector_type(4)));
typedef float f32x4 __attribute__((ext_vector_type(4)));

// Device-coherent (MALL meeting point) ops — proven R6/R7/R12 path. sc0 sc1 bypasses
// stale L1/L2; always correct cross-XCD.
__device__ __forceinline__ bf16x8 ld_coh16(const __bf16* p) {
    bf16x8 v;
    asm volatile("global_load_dwordx4 %0, %1, off sc0 sc1"
                 : "=v"(v) : "v"((const void*)p) : "memory");
    return v;
}
__device__ __forceinline__ void st_coh16(__bf16* p, bf16x8 v) {
    asm volatile("global_store_dwordx4 %0, %1, off sc0 sc1"
                 :: "v"((void*)p), "v"(v) : "memory");
}
__device__ __forceinline__ void st_coh4(unsigned* p, unsigned v) {
    asm volatile("global_store_dword %0, %1, off sc0 sc1"
                 :: "v"((void*)p), "v"(v) : "memory");
}
__device__ __forceinline__ unsigned ld_coh4(const unsigned* p) {
    unsigned v;
    asm volatile("global_load_dword %0, %1, off sc0 sc1"
                 : "=v"(v) : "v"((const void*)p) : "memory");
    asm volatile("s_waitcnt vmcnt(0)" ::: "memory");
    return v;
}

// HW-native transcendentals (v_exp_f32 = 2^x, v_rcp_f32) — replace libm expf/tanhf
// (15-30 branchy VALU ops each) in the serial gate-math chain. Saturation exact:
// sigmoid -> rcp(inf)=0 / rcp(1)=1; tanh -> +/-1. Rel err ~1e-6 << bf16 noise.
__device__ __forceinline__ float fexp2(float x) {
    float r; asm("v_exp_f32 %0, %1" : "=v"(r) : "v"(x)); return r;
}
__device__ __forceinline__ float frcp(float x) {
    float r; asm("v_rcp_f32 %0, %1" : "=v"(r) : "v"(x)); return r;
}
__device__ __forceinline__ float fsig(float x) {      // 1/(1+e^-x)
    return frcp(1.f + fexp2(-1.442695041f * x));
}
__device__ __forceinline__ float ftanh(float x) {     // 1 - 2/(e^2x+1)
    return 1.f - 2.f * frcp(fexp2(2.885390082f * x) + 1.f);
}

// ---------------- prefix scan of lengths -> starts; zero barrier slots ----------------
__global__ __launch_bounds__(BATCH) void scan_kernel(const int* __restrict__ len,
                                                     int* __restrict__ starts,
                                                     unsigned* __restrict__ ctr) {
    __shared__ int buf[BATCH];
    int tid = threadIdx.x;
    ctr[tid] = 0u;                    // 1024 slots: [16 grp][4 wid][16 hc]
    ctr[tid + BATCH] = 0u;            // re-zeroed every launch (graph-replay determinism)
    int myLen = len[tid];
    buf[tid] = myLen;
    __syncthreads();
    for (int off = 1; off < BATCH; off <<= 1) {
        int v = (tid >= off) ? buf[tid - off] : 0;
        __syncthreads();
        buf[tid] += v;
        __syncthreads();
    }
    starts[tid] = buf[tid] - myLen;   // exclusive scan
}

// ------- h0 = segment_max(h) (fp32 + bf16 into scan buffer 0, both dirs) -------
__global__ __launch_bounds__(HID) void init_kernel(const float* __restrict__ h,
                                                   const int* __restrict__ len,
                                                   const int* __restrict__ starts,
                                                   float* __restrict__ h0,     // [B][H]
                                                   __bf16* __restrict__ hb) {  // buf0: [2][B][H]
    int b = blockIdx.x, j = threadIdx.x;
    int s = starts[b], L = len[b];
    const float* hp = h + (size_t)s * HID + j;
    float m0 = -3.4e38f, m1 = -3.4e38f, m2 = -3.4e38f, m3 = -3.4e38f;
    int t = 0;
    for (; t + 3 < L; t += 4) {
        m0 = fmaxf(m0, hp[(size_t)(t + 0) * HID]);
        m1 = fmaxf(m1, hp[(size_t)(t + 1) * HID]);
        m2 = fmaxf(m2, hp[(size_t)(t + 2) * HID]);
        m3 = fmaxf(m3, hp[(size_t)(t + 3) * HID]);
    }
    for (; t < L; ++t) m0 = fmaxf(m0, hp[(size_t)t * HID]);
    float m = fmaxf(fmaxf(m0, m1), fmaxf(m2, m3));
    h0[(size_t)b * HID + j] = m;
    hb[(size_t)b * HID + j] = (__bf16)m;
    hb[(size_t)(BATCH + b) * HID + j] = (__bf16)m;
}

// ---------------- message = relu(h + bias) -> bf16 ----------------
__global__ void msg_kernel(const float* __restrict__ h, const float* __restrict__ bias,
                           __bf16* __restrict__ msg, long total4) {
    for (long i = (long)blockIdx.x * blockDim.x + threadIdx.x; i < total4;
         i += (long)gridDim.x * blockDim.x) {
        float4 v = ((const float4*)h)[i];
        int c4 = (int)(i & (HID / 4 - 1));
        float4 bb = ((const float4*)bias)[c4];
        bf16x4 o;
        o[0] = (__bf16)fmaxf(v.x + bb.x, 0.f);
        o[1] = (__bf16)fmaxf(v.y + bb.y, 0.f);
        o[2] = (__bf16)fmaxf(v.z + bb.z, 0.f);
        o[3] = (__bf16)fmaxf(v.w + bb.w, 0.f);
        ((bf16x4*)msg)[i] = o;
    }
}

// ---------------- fp32 -> bf16 weight convert ----------------
__global__ void conv_kernel(const float* __restrict__ src, __bf16* __restrict__ dst, int n4) {
    int i = blockIdx.x * blockDim.x + threadIdx.x;
    if (i < n4) {
        float4 v = ((const float4*)src)[i];
        bf16x4 o;
        o[0] = (__bf16)v.x; o[1] = (__bf16)v.y; o[2] = (__bf16)v.z; o[3] = (__bf16)v.w;
        ((bf16x4*)dst)[i] = o;
    }
}

// ---------------- gx = msg @ w_ih^T  (NT GEMM, bf16 out) — R15 v3, frozen ----------------
__global__ __launch_bounds__(256) void gx_gemm(const __bf16* __restrict__ msg,
                                               const __bf16* __restrict__ wih,  // [2][1536][512]
                                               __bf16* __restrict__ gx,         // [2][N][1536]
                                               int N) {
    __shared__ __bf16 alds[64 * 512];    // 64KB, rows of 1KB, 16B-chunk XOR swizzle
    __shared__ __bf16 ctile[4][16 * 40]; // 5KB: per-wave private C repack
    int dir = blockIdx.y;
    int r0 = blockIdx.x * 64;
    int wid = threadIdx.x >> 6, lane = threadIdx.x & 63;
    int lrow = lane & 15, lk = lane >> 4;
    const __bf16* wB = wih + (size_t)dir * H3 * HID;
    __bf16* gOut = gx + (size_t)dir * N * H3;

    for (int i = threadIdx.x; i < 64 * 64; i += 256) {
        int row = i >> 6, ch = i & 63;
        int sch = ch ^ (row & 7);
        int grow = r0 + row; if (grow >= N) grow = N - 1;
        *(bf16x8*)(&alds[row * 512 + sch * 8]) = *(const bf16x8*)(msg + (size_t)grow * HID + ch * 8);
    }
    __syncthreads();

    for (int ct = 0; ct < 12; ++ct) {
        int c0 = ct * 128 + wid * 32;
        f32x4 acc[4][2] = {};
#pragma unroll
        for (int ks = 0; ks < 16; ++ks) {
            bf16x8 b0 = *(const bf16x8*)(wB + (size_t)(c0 + lrow) * HID + ks * 32 + lk * 8);
            bf16x8 b1 = *(const bf16x8*)(wB + (size_t)(c0 + 16 + lrow) * HID + ks * 32 + lk * 8);
#pragma unroll
            for (int rf = 0; rf < 4; ++rf) {
                int row = rf * 16 + lrow;
                int sch = (ks * 4 + lk) ^ (row & 7);
                bf16x8 av = *(const bf16x8*)(&alds[row * 512 + sch * 8]);
                acc[rf][0] = __builtin_amdgcn_mfma_f32_16x16x32_bf16(av, b0, acc[rf][0], 0, 0, 0);
                acc[rf][1] = __builtin_amdgcn_mfma_f32_16x16x32_bf16(av, b1, acc[rf][1], 0, 0, 0);
            }
        }
#pragma unroll
        for (int rf = 0; rf < 4; ++rf) {
#pragma unroll
            for (int fj = 0; fj < 2; ++fj)
#pragma unroll
                for (int r = 0; r < 4; ++r)
                    ctile[wid][(lk * 4 + r) * 40 + fj * 16 + lrow] = (__bf16)acc[rf][fj][r];
            asm volatile("s_waitcnt lgkmcnt(0)" ::: "memory");
            int row = r0 + rf * 16 + (lane >> 2);
            if (row < N) {
                bf16x8 v = *(const bf16x8*)(&ctile[wid][(lane >> 2) * 40 + (lane & 3) * 8]);
                *(bf16x8*)(gOut + (size_t)row * H3 + c0 + (lane & 3) * 8) = v;
            }
            asm volatile("s_waitcnt lgkmcnt(0)" ::: "memory");
        }
    }
}

// ================= persistent GRU scan — PER-WAVE flags (R12) + fast gates =================
__global__ __launch_bounds__(256, 1) void gru_scan(
    const __bf16* __restrict__ whh,   // [2][1536][512]
    const __bf16* __restrict__ gx,    // [2][N][1536]
    const float* __restrict__ h0,     // [B][H]
    __bf16* __restrict__ hb,          // [2 bufs][2 dirs][B][H]
    const float* __restrict__ b_ih_f, const float* __restrict__ b_hh_f,
    const float* __restrict__ b_ih_b, const float* __restrict__ b_hh_b,
    const int* __restrict__ len, const int* __restrict__ starts,
    unsigned* __restrict__ ctr,       // [16 grp][4 wid][16 hc] u32 = 4KB
    float* __restrict__ out, int N) {

    __shared__ __bf16 wlds[96 * 512];    // 96KB W tile, 16B-chunk XOR swizzle
    __shared__ __bf16 hout[4][16 * 40];  // per-wave private repack (no cross-wave sync)

    int bid = blockIdx.x;
    int rg  = bid & 7;
    int dir = (bid >> 3) & 1;
    int hc  = bid >> 4;
    int grp = dir * 8 + rg;
    int wid = threadIdx.x >> 6, lane = threadIdx.x & 63;
    int r0 = rg * 64;
    int c0 = hc * 32;

    for (int i = threadIdx.x; i < 96 * 64; i += 256) {
        int row = i >> 6, ch = i & 63;
        int g = row >> 5, c = row & 31;
        int sch = ch ^ (row & 7);
        const __bf16* src = whh + ((size_t)dir * H3 + (size_t)g * HID + c0 + c) * HID + ch * 8;
        *(bf16x8*)(&wlds[row * 512 + sch * 8]) = *(const bf16x8*)src;
    }

    int wr0 = r0 + wid * 16;
    int lrow = lane & 15;
    int lk   = lane >> 4;

    int mycol[2], myrow[4];
#pragma unroll
    for (int fj = 0; fj < 2; ++fj) mycol[fj] = c0 + fj * 16 + (lane & 15);
#pragma unroll
    for (int r = 0; r < 4; ++r) myrow[r] = wr0 + (lane >> 4) * 4 + r;

    float hreg[2][4], sreg[2][4];
#pragma unroll
    for (int fj = 0; fj < 2; ++fj)
#pragma unroll
        for (int r = 0; r < 4; ++r) {
            hreg[fj][r] = h0[(size_t)myrow[r] * HID + mycol[fj]];
            sreg[fj][r] = 0.f;
        }

    const float* bih = dir ? b_ih_b : b_ih_f;
    const float* bhh = dir ? b_hh_b : b_hh_f;
    float bihv[2][3], bhhv[2][3];
#pragma unroll
    for (int fj = 0; fj < 2; ++fj)
#pragma unroll
        for (int g = 0; g < 3; ++g) {
            bihv[fj][g] = bih[g * HID + mycol[fj]];
            bhhv[fj][g] = bhh[g * HID + mycol[fj]];
        }
    int mylen[4], mystart[4];
#pragma unroll
    for (int r = 0; r < 4; ++r) { mylen[r] = len[myrow[r]]; mystart[r] = starts[myrow[r]]; }

    // gx prefetch for step 0
    float gxv[2][4][3];
    {
        int t = dir ? (MAXL - 1) : 0;
#pragma unroll
        for (int r = 0; r < 4; ++r) {
            bool real = t < mylen[r];
            size_t base = ((size_t)dir * N + mystart[r] + t) * H3;
#pragma unroll
            for (int fj = 0; fj < 2; ++fj)
#pragma unroll
                for (int g = 0; g < 3; ++g)
                    gxv[fj][r][g] = real ? (float)gx[base + (size_t)g * HID + mycol[fj]] : 0.f;
        }
    }

    __syncthreads();   // wlds ready — only block-wide sync in this kernel

    const size_t bufStride = (size_t)2 * BATCH * HID;
    const size_t stoff = (size_t)(wr0 + (lane >> 2)) * HID + c0 + (lane & 3) * 8;
    unsigned* myArrive = ctr + grp * 64 + wid * 16 + hc;
    const unsigned* myPoll = ctr + grp * 64 + wid * 16 + (lane & 15);

    for (int s = 0; s < MAXL; ++s) {
        int t = dir ? (MAXL - 1 - s) : s;
        const __bf16* hcur = hb + (size_t)(s & 1) * bufStride + (size_t)dir * BATCH * HID;
        __bf16* hnxt = hb + (size_t)((s + 1) & 1) * bufStride + (size_t)dir * BATCH * HID;

        // ---- A: this wave's [16 rows x 512 K] via coherent 16B loads, all in flight
        bf16x8 a[16];
#pragma unroll
        for (int ks = 0; ks < 16; ++ks)
            a[ks] = ld_coh16(hcur + (size_t)(wr0 + lrow) * HID + ks * 32 + lk * 8);
        asm volatile("s_waitcnt vmcnt(0)" ::: "memory");
        __builtin_amdgcn_sched_barrier(0);   // keep MFMAs below the waitcnt (rule 18)

        // ---- GEMM: gh = h @ whh^T, 3 gates x 2 col-frags
        f32x4 acc[3][2] = {};
#pragma unroll
        for (int ks = 0; ks < 16; ++ks) {
#pragma unroll
            for (int g = 0; g < 3; ++g) {
#pragma unroll
                for (int f = 0; f < 2; ++f) {
                    int row = g * 32 + f * 16 + lrow;
                    int sch = (ks * 4 + lk) ^ (row & 7);
                    bf16x8 b = *(const bf16x8*)(&wlds[row * 512 + sch * 8]);
                    acc[g][f] = __builtin_amdgcn_mfma_f32_16x16x32_bf16(a[ks], b, acc[g][f], 0, 0, 0);
                }
            }
        }

        // ---- gate math + state update (fp32, HW-native sigmoid/tanh)
#pragma unroll
        for (int fj = 0; fj < 2; ++fj)
#pragma unroll
            for (int r = 0; r < 4; ++r) {
                float ghr = acc[0][fj][r] + bhhv[fj][0];
                float ghz = acc[1][fj][r] + bhhv[fj][1];
                float ghn = acc[2][fj][r] + bhhv[fj][2];
                float xr = gxv[fj][r][0] + bihv[fj][0];
                float xz = gxv[fj][r][1] + bihv[fj][1];
                float xn = gxv[fj][r][2] + bihv[fj][2];
                float rg_ = fsig(xr + ghr);
                float zg  = fsig(xz + ghz);
                float ng  = ftanh(xn + rg_ * ghn);
                float hn  = (1.f - zg) * ng + zg * hreg[fj][r];
                hreg[fj][r] = hn;
                if (t < mylen[r]) sreg[fj][r] += hn;
            }

        if (s + 1 == MAXL) break;   // no exchange after last step

        // ---- per-wave repack (wave-internal LDS ordering) + per-wave 16B stores
#pragma unroll
        for (int fj = 0; fj < 2; ++fj)
#pragma unroll
            for (int r = 0; r < 4; ++r)
                hout[wid][(lk * 4 + r) * 40 + fj * 16 + lrow] = (__bf16)hreg[fj][r];
        {
            bf16x8 v = *(const bf16x8*)(&hout[wid][(lane >> 2) * 40 + (lane & 3) * 8]);
            st_coh16(hnxt + stoff, v);
        }
        // drain THIS WAVE's store (per-wave vmcnt), then arrive on own slot
        asm volatile("s_waitcnt vmcnt(0)" ::: "memory");
        if (lane == 0) st_coh4(myArrive, (unsigned)(s + 1));

        // gx prefetch for step s+1 — flies under the poll
        {
            int tn = dir ? (MAXL - 2 - s) : (s + 1);
#pragma unroll
            for (int r = 0; r < 4; ++r) {
                bool real = tn < mylen[r];
                size_t base = ((size_t)dir * N + mystart[r] + tn) * H3;
#pragma unroll
                for (int fj = 0; fj < 2; ++fj)
#pragma unroll
                    for (int g = 0; g < 3; ++g)
                        gxv[fj][r][g] = real ? (float)gx[base + (size_t)g * HID + mycol[fj]] : 0.f;
            }
        }

        // ---- poll: all lanes watch the 16 same-wid slots (one 64B line)
        {
            unsigned tgt = (unsigned)(s + 1);
            for (;;) {
                unsigned v = ld_coh4(myPoll);
                if (__ballot(v < tgt) == 0ull) break;
                __builtin_amdgcn_s_sleep(1);
            }
        }
        asm volatile("" ::: "memory");       // no compiler motion across the spin exit
        __builtin_amdgcn_sched_barrier(0);   // keep next A-loads after it
    }

    // ---- final output: out[row][dir*H + col] = sum / len
#pragma unroll
    for (int fj = 0; fj < 2; ++fj)
#pragma unroll
        for (int r = 0; r < 4; ++r)
            out[(size_t)myrow[r] * (2 * HID) + (size_t)dir * HID + mycol[fj]] =
                sreg[fj][r] / (float)mylen[r];
}

extern "C" void kernel_launch(void* const* d_in, const int* in_sizes, int n_in,
                              void* d_out, int out_size, void* d_ws, size_t ws_size,
                              hipStream_t stream) {
    const float* h      = (const float*)d_in[0];
    const int*   lens   = (const int*)d_in[1];
    const float* bias   = (const float*)d_in[2];
    const float* w_ih_f = (const float*)d_in[3];
    const float* w_hh_f = (const float*)d_in[4];
    const float* b_ih_f = (const float*)d_in[5];
    const float* b_hh_f = (const float*)d_in[6];
    const float* w_ih_b = (const float*)d_in[7];
    const float* w_hh_b = (const float*)d_in[8];
    const float* b_ih_b = (const float*)d_in[9];
    const float* b_hh_b = (const float*)d_in[10];
    float* out = (float*)d_out;
    const int N = in_sizes[0] / HID;

    // workspace layout — identical to the R12 passing layout
    char* p = (char*)d_ws;
    size_t off = 0;
    int* starts   = (int*)(p + off);        off += 4096;
    unsigned* ctr = (unsigned*)(p + off);   off += 4096;   // 1024 u32 flag slots
    float* h0   = (float*)(p + off);        off += (size_t)BATCH * HID * 4;
    __bf16* hb  = (__bf16*)(p + off);       off += (size_t)2 * 2 * BATCH * HID * 2;
    __bf16* wih = (__bf16*)(p + off);       off += (size_t)2 * H3 * HID * 2;
    __bf16* whh = (__bf16*)(p + off);       off += (size_t)2 * H3 * HID * 2;
    __bf16* msg = (__bf16*)(p + off);       off += (size_t)N * HID * 2;
    __bf16* gx  = (__bf16*)(p + off);       off += (size_t)2 * N * H3 * 2;
    if (off > ws_size) return;  // interpretable failure: output stays zero

    scan_kernel<<<1, BATCH, 0, stream>>>(lens, starts, ctr);
    init_kernel<<<BATCH, HID, 0, stream>>>(h, lens, starts, h0, hb);

    long total4 = (long)N * HID / 4;
    int msgBlocks = (int)((total4 + 255) / 256); if (msgBlocks > 2048) msgBlocks = 2048;
    msg_kernel<<<msgBlocks, 256, 0, stream>>>(h, bias, msg, total4);

    int n4 = H3 * HID / 4;
    int cb = (n4 + 255) / 256;
    conv_kernel<<<cb, 256, 0, stream>>>(w_ih_f, wih, n4);
    conv_kernel<<<cb, 256, 0, stream>>>(w_ih_b, wih + (size_t)H3 * HID, n4);
    conv_kernel<<<cb, 256, 0, stream>>>(w_hh_f, whh, n4);
    conv_kernel<<<cb, 256, 0, stream>>>(w_hh_b, whh + (size_t)H3 * HID, n4);

    gx_gemm<<<dim3((N + 63) / 64, 2), 256, 0, stream>>>(msg, wih, gx, N);

    int Nv = N;
    void* kargs[] = {(void*)&whh, (void*)&gx, (void*)&h0, (void*)&hb,
                     (void*)&b_ih_f, (void*)&b_hh_f, (void*)&b_ih_b, (void*)&b_hh_b,
                     (void*)&lens, (void*)&starts, (void*)&ctr, (void*)&out, (void*)&Nv};
    hipLaunchCooperativeKernel((const void*)gru_scan, dim3(256), dim3(256), kargs, 0, stream);
}